// Round 10
// baseline (1086.387 us; speedup 1.0000x reference)
//
#include <hip/hip_runtime.h>
#include <math.h>

#define HD 64
#define FIN 512
#define NC 40

struct __align__(8) EdgeT { int s; float v; };

typedef __attribute__((ext_vector_type(8))) short bf16x8;
typedef __attribute__((ext_vector_type(8))) unsigned short u16x8;
typedef __attribute__((ext_vector_type(4))) float f32x4;

__device__ __forceinline__ float bf2f(ushort u) {
    return __uint_as_float(((unsigned int)u) << 16);
}
__device__ __forceinline__ ushort f2bf(float f) {
    unsigned int u = __float_as_uint(f);
    unsigned int r = (u + 0x7fffu + ((u >> 16) & 1u)) >> 16;   // RNE
    return (ushort)r;
}

// ---------------- graph preprocessing ----------------
// packed8[c*n+i]: bits[48:64) = edge count, bits[0:48) = fixed-point(2^-32) weighted degree.

__global__ __launch_bounds__(256) void initp_kernel(unsigned long long* packed8,
        int* dhist, int n) {
    int i = blockIdx.x * 256 + threadIdx.x;
    if (i < 8 * n) packed8[i] = (i < n) ? (1ULL << 32) : 0ULL;  // self-loop w=1 in copy 0
    if (i < 256) dhist[i] = 0;
}

__global__ __launch_bounds__(256) void histp_kernel(const int* __restrict__ dst,
        const float* __restrict__ w, unsigned long long* packed8,
        ushort* __restrict__ rank, int E, int n) {
    int i = blockIdx.x * 256 + threadIdx.x;
    if (i < E) {
        int d = dst[i];
        int c = i & 7;
        unsigned long long add = (1ULL << 48) |
            (unsigned long long)(w[i] * 4294967296.0f);
        unsigned long long old = atomicAdd(&packed8[(size_t)c * n + d], add);
        rank[i] = (ushort)(old >> 48);
    }
}

// fused: dinv + copy-bases + per-block count scan + degree histogram
__global__ __launch_bounds__(256) void post_kernel(const unsigned long long* __restrict__ packed8,
        float* __restrict__ dinv, uint2* __restrict__ cbase,
        int* __restrict__ row_ptr, int* __restrict__ bsums,
        ushort* __restrict__ degc, int* __restrict__ dhist, int n) {
    __shared__ int s[256];
    const unsigned long long M = 0xFFFFFFFFFFFFULL;
    int t = threadIdx.x;
    int i = blockIdx.x * 256 + t;
    int cnt = 0;
    if (i < n) {
        int c[8];
        unsigned long long fx = 0;
#pragma unroll
        for (int k = 0; k < 8; ++k) {
            unsigned long long p = packed8[(size_t)k * n + i];
            c[k] = (int)(p >> 48);
            fx += (p & M);
        }
        float deg = (float)((double)fx * (1.0 / 4294967296.0));
        dinv[i] = rsqrtf(deg);                     // deg >= 1 (self-loop)
        int b = 0; uint lo = 0, hi = 0;
#pragma unroll
        for (int k = 0; k < 4; ++k) { lo |= ((uint)b) << (8 * k); b += c[k]; }
#pragma unroll
        for (int k = 0; k < 4; ++k) { hi |= ((uint)b) << (8 * k); b += c[4 + k]; }
        cbase[i] = make_uint2(lo, hi);
        cnt = b;
        int bin = cnt < 255 ? cnt : 255;
        degc[i] = (ushort)bin;
        atomicAdd(&dhist[bin], 1);
    }
    s[t] = cnt; __syncthreads();
    for (int off = 1; off < 256; off <<= 1) {
        int u = (t >= off) ? s[t - off] : 0;
        __syncthreads();
        s[t] += u;
        __syncthreads();
    }
    if (i < n) row_ptr[i] = s[t] - cnt;
    if (t == 255) bsums[blockIdx.x] = s[255];
}

__global__ __launch_bounds__(512) void scan_top_kernel(int* bsums, int nb) {
    __shared__ int s[512];
    int t = threadIdx.x;
    int v = (t < nb) ? bsums[t] : 0;
    s[t] = v; __syncthreads();
    for (int off = 1; off < 512; off <<= 1) {
        int u = (t >= off) ? s[t - off] : 0;
        __syncthreads();
        s[t] += u;
        __syncthreads();
    }
    if (t < nb) bsums[t] = s[t] - v;
}

__global__ __launch_bounds__(256) void scan_add_kernel(int* __restrict__ row_ptr,
        const int* __restrict__ bsums, int n, int E) {
    int i = blockIdx.x * 256 + threadIdx.x;
    if (i < n) row_ptr[i] += bsums[blockIdx.x];
    if (i == 0) row_ptr[n] = E;
}

// exclusive scan of 256-bin degree histogram -> dcursor
__global__ __launch_bounds__(256) void binscan_kernel(const int* __restrict__ dhist,
        int* __restrict__ dcursor) {
    __shared__ int s[256];
    int t = threadIdx.x;
    int v = dhist[t];
    s[t] = v; __syncthreads();
    for (int off = 1; off < 256; off <<= 1) {
        int u = (t >= off) ? s[t - off] : 0;
        __syncthreads();
        s[t] += u;
        __syncthreads();
    }
    dcursor[t] = s[t] - v;
}

// counting-sort node ids by degree bin
__global__ __launch_bounds__(256) void order_kernel(const ushort* __restrict__ degc,
        int* __restrict__ dcursor, int* __restrict__ order, int n) {
    int i = blockIdx.x * 256 + threadIdx.x;
    if (i < n) {
        int bin = degc[i];
        int pos = atomicAdd(&dcursor[bin], 1);
        order[pos] = i;
    }
}

__global__ __launch_bounds__(256) void scatter_kernel(const int* __restrict__ src,
        const int* __restrict__ dst, const float* __restrict__ w,
        const float* __restrict__ dinv, const int* __restrict__ row_ptr,
        const uint2* __restrict__ cbase, const ushort* __restrict__ rank,
        EdgeT* __restrict__ ed, int E) {
    int i = blockIdx.x * 256 + threadIdx.x;
    if (i < E) {
        int s = src[i], d = dst[i];
        int c = i & 7;
        uint2 cb = cbase[d];
        int base = (int)(((c < 4) ? (cb.x >> (8 * c)) : (cb.y >> (8 * (c - 4)))) & 0xffu);
        int pos = row_ptr[d] + base + (int)rank[i];
        EdgeT e; e.s = s; e.v = dinv[s] * w[i] * dinv[d];
        ed[pos] = e;
    }
}

// setup: W_out zero-pad + b_out pad + W_in -> bf16 fragment-major
__global__ __launch_bounds__(256) void setup_kernel(const float* __restrict__ W,
        ushort* __restrict__ Wf, const float* __restrict__ Wo,
        const float* __restrict__ bo, float* __restrict__ Wo_pad,
        float* __restrict__ bo_pad) {
    int i = blockIdx.x * 256 + threadIdx.x;
    if (i < FIN * HD) {
        int j = i & 7;
        int l = (i >> 3) & 63;
        int t = (i >> 9) & 3;
        int c = i >> 11;
        int k = c * 32 + ((l >> 4) * 8) + j;
        int col = t * 16 + (l & 15);
        Wf[i] = f2bf(W[k * HD + col]);
    }
    if (i < HD * HD) {
        int k = i >> 6, c2 = i & 63;
        Wo_pad[i] = (c2 < NC) ? Wo[k * NC + c2] : 0.f;
    }
    if (i < HD) bo_pad[i] = (i < NC) ? bo[i] : 0.f;
}

// ---------------- SpMM v5 (bf16 h, 8 nodes/wave, degree-sorted): agg = Ahat@h_in ----
// 8 lanes per node; lane owns feature octet (lane&7)*8 (16B loads). Nodes taken in
// degree-sorted order so all 8 nodes in a wave have ~equal row length (no divergence
// waste). Residual applied later in lgemm staging.

__global__ __launch_bounds__(256) void spmm_kernel(const ushort* __restrict__ h_in,
        ushort* __restrict__ agg, const float* __restrict__ dinv,
        const int* __restrict__ row_ptr, const EdgeT* __restrict__ ed,
        const int* __restrict__ order, int n) {
    const int lane = threadIdx.x & 63;
    const int g = lane >> 3;               // node slot 0..7
    const int fl = (lane & 7) * 8;         // feature offset
    int oct = (blockIdx.x * 256 + threadIdx.x) >> 6;
    int idx = oct * 8 + g;
    bool valid = idx < n;
    int node = order[valid ? idx : n - 1];

    float di = dinv[node];
    float sw = di * di;
    u16x8 us = *(const u16x8*)(h_in + (size_t)node * HD + fl);
    float a[8], b[8];
#pragma unroll
    for (int j = 0; j < 8; ++j) { a[j] = sw * bf2f((ushort)us[j]); b[j] = 0.f; }

    int e = row_ptr[node], end = row_ptr[node + 1];
    for (; e + 8 <= end; e += 8) {
        EdgeT Ex[8];
        u16x8 ux[8];
#pragma unroll
        for (int k = 0; k < 8; ++k) Ex[k] = ed[e + k];
#pragma unroll
        for (int k = 0; k < 8; ++k)
            ux[k] = *(const u16x8*)(h_in + (size_t)Ex[k].s * HD + fl);
#pragma unroll
        for (int k = 0; k < 8; k += 2) {
#pragma unroll
            for (int j = 0; j < 8; ++j) {
                a[j] = fmaf(Ex[k].v,     bf2f((ushort)ux[k][j]),     a[j]);
                b[j] = fmaf(Ex[k + 1].v, bf2f((ushort)ux[k + 1][j]), b[j]);
            }
        }
    }
    for (; e + 2 <= end; e += 2) {
        EdgeT E0 = ed[e], E1 = ed[e + 1];
        u16x8 u0 = *(const u16x8*)(h_in + (size_t)E0.s * HD + fl);
        u16x8 u1 = *(const u16x8*)(h_in + (size_t)E1.s * HD + fl);
#pragma unroll
        for (int j = 0; j < 8; ++j) {
            a[j] = fmaf(E0.v, bf2f((ushort)u0[j]), a[j]);
            b[j] = fmaf(E1.v, bf2f((ushort)u1[j]), b[j]);
        }
    }
    if (e < end) {
        EdgeT E0 = ed[e];
        u16x8 u0 = *(const u16x8*)(h_in + (size_t)E0.s * HD + fl);
#pragma unroll
        for (int j = 0; j < 8; ++j) a[j] = fmaf(E0.v, bf2f((ushort)u0[j]), a[j]);
    }

    if (valid) {
        u16x8 r;
#pragma unroll
        for (int j = 0; j < 8; ++j) r[j] = f2bf(a[j] + b[j]);
        *(u16x8*)(agg + (size_t)node * HD + fl) = r;
    }
}

// ---------------- proj (MFMA): h0 = relu(x @ W_in + b_in) -> bf16 ----------------

__global__ __launch_bounds__(256) void projm_kernel(const float* __restrict__ x,
        const ushort* __restrict__ Wf, const float* __restrict__ bias,
        ushort* __restrict__ h0, int n) {
    const int lane = threadIdx.x & 63;
    const int wave = threadIdx.x >> 6;
    const int row = lane & 15;
    const int g = lane >> 4;
    const int base = blockIdx.x * 128 + wave * 32;

    f32x4 acc[2][4];
#pragma unroll
    for (int m = 0; m < 2; ++m)
#pragma unroll
        for (int t = 0; t < 4; ++t) acc[m][t] = (f32x4){0.f, 0.f, 0.f, 0.f};

    for (int c = 0; c < 16; ++c) {
        bf16x8 afr[2];
#pragma unroll
        for (int m = 0; m < 2; ++m) {
            int node = base + m * 16 + row;
            if (node >= n) node = n - 1;
            const float* p = x + (size_t)node * FIN + c * 32 + g * 8;
            float4 v0 = *(const float4*)p;
            float4 v1 = *(const float4*)(p + 4);
            afr[m][0] = (short)f2bf(v0.x); afr[m][1] = (short)f2bf(v0.y);
            afr[m][2] = (short)f2bf(v0.z); afr[m][3] = (short)f2bf(v0.w);
            afr[m][4] = (short)f2bf(v1.x); afr[m][5] = (short)f2bf(v1.y);
            afr[m][6] = (short)f2bf(v1.z); afr[m][7] = (short)f2bf(v1.w);
        }
#pragma unroll
        for (int t = 0; t < 4; ++t) {
            bf16x8 bfr = *(const bf16x8*)(Wf + ((size_t)(c * 4 + t) * 64 + lane) * 8);
            acc[0][t] = __builtin_amdgcn_mfma_f32_16x16x32_bf16(afr[0], bfr, acc[0][t], 0, 0, 0);
            acc[1][t] = __builtin_amdgcn_mfma_f32_16x16x32_bf16(afr[1], bfr, acc[1][t], 0, 0, 0);
        }
    }

    float bj[4];
#pragma unroll
    for (int t = 0; t < 4; ++t) bj[t] = bias[t * 16 + row];
#pragma unroll
    for (int m = 0; m < 2; ++m)
#pragma unroll
        for (int r = 0; r < 4; ++r) {
            int node = base + m * 16 + g * 4 + r;
            if (node < n) {
#pragma unroll
                for (int t = 0; t < 4; ++t) {
                    float v = fmaxf(acc[m][t][r] + bj[t], 0.f);
                    h0[(size_t)node * HD + t * 16 + row] = f2bf(v);
                }
            }
        }
}

// ---------------- layer / output GEMM over bf16 A, fp32 W, K=64 ----------------
// MODE 1: Af = 0.9*agg + 0.1*h0 (f32); C = relu(beta*(Af@W) + (1-beta)*Af) -> bf16
// MODE 2: log_softmax(A@W + bias) over first NC cols -> outp fp32

template<int MODE>
__global__ __launch_bounds__(256) void lgemm_kernel(const ushort* __restrict__ A,
        const ushort* __restrict__ h0r, const float* __restrict__ W,
        const float* __restrict__ bias, ushort* __restrict__ C,
        float* __restrict__ outp, int n, float beta) {
    __shared__ float Af[64 * 68];
    __shared__ float Wl[64 * 64];
    const int tid = threadIdx.x;
    const int tx = tid & 15;
    const int ty = tid >> 4;
    const int base = blockIdx.x * 64;
    const int kq = (tid & 15) * 4;
    const int rw = tid >> 4;

#pragma unroll
    for (int p = 0; p < 4; ++p) {
        int row = rw + p * 16;
        int ng = base + row; if (ng >= n) ng = n - 1;
        ushort4 u = *(const ushort4*)(A + (size_t)ng * HD + kq);
        if constexpr (MODE == 1) {
            ushort4 uh = *(const ushort4*)(h0r + (size_t)ng * HD + kq);
            Af[row * 68 + kq + 0] = fmaf(0.9f, bf2f(u.x), 0.1f * bf2f(uh.x));
            Af[row * 68 + kq + 1] = fmaf(0.9f, bf2f(u.y), 0.1f * bf2f(uh.y));
            Af[row * 68 + kq + 2] = fmaf(0.9f, bf2f(u.z), 0.1f * bf2f(uh.z));
            Af[row * 68 + kq + 3] = fmaf(0.9f, bf2f(u.w), 0.1f * bf2f(uh.w));
        } else {
            Af[row * 68 + kq + 0] = bf2f(u.x);
            Af[row * 68 + kq + 1] = bf2f(u.y);
            Af[row * 68 + kq + 2] = bf2f(u.z);
            Af[row * 68 + kq + 3] = bf2f(u.w);
        }
        *(float4*)(Wl + row * 64 + kq) =
            *(const float4*)(W + (size_t)row * HD + kq);
    }
    __syncthreads();

    float acc[4][4];
#pragma unroll
    for (int i = 0; i < 4; ++i)
#pragma unroll
        for (int j = 0; j < 4; ++j) acc[i][j] = 0.f;

#pragma unroll
    for (int kk = 0; kk < 64; kk += 4) {
        float4 a4[4];
#pragma unroll
        for (int i = 0; i < 4; ++i)
            a4[i] = *(const float4*)(Af + (ty * 4 + i) * 68 + kk);
#pragma unroll
        for (int k2 = 0; k2 < 4; ++k2) {
            float w[4];
            *(float4*)w = *(const float4*)(Wl + (kk + k2) * 64 + tx * 4);
#pragma unroll
            for (int i = 0; i < 4; ++i) {
                float a = ((const float*)&a4[i])[k2];
#pragma unroll
                for (int j = 0; j < 4; ++j) acc[i][j] = fmaf(a, w[j], acc[i][j]);
            }
        }
    }

    if constexpr (MODE == 1) {
        const float ombeta = 1.f - beta;
#pragma unroll
        for (int i = 0; i < 4; ++i) {
            int ng = base + ty * 4 + i;
            if (ng < n) {
                ushort4 r;
                float s0 = Af[(ty * 4 + i) * 68 + tx * 4 + 0];
                float s1 = Af[(ty * 4 + i) * 68 + tx * 4 + 1];
                float s2 = Af[(ty * 4 + i) * 68 + tx * 4 + 2];
                float s3 = Af[(ty * 4 + i) * 68 + tx * 4 + 3];
                r.x = f2bf(fmaxf(fmaf(beta, acc[i][0], ombeta * s0), 0.f));
                r.y = f2bf(fmaxf(fmaf(beta, acc[i][1], ombeta * s1), 0.f));
                r.z = f2bf(fmaxf(fmaf(beta, acc[i][2], ombeta * s2), 0.f));
                r.w = f2bf(fmaxf(fmaf(beta, acc[i][3], ombeta * s3), 0.f));
                *(ushort4*)(C + (size_t)ng * HD + tx * 4) = r;
            }
        }
    } else {
        float b[4];
#pragma unroll
        for (int j = 0; j < 4; ++j) b[j] = bias[tx * 4 + j];
        const bool valid = (tx < 10);
#pragma unroll
        for (int i = 0; i < 4; ++i) {
            float lo[4];
            float m = -3.0e38f;
#pragma unroll
            for (int j = 0; j < 4; ++j) {
                lo[j] = acc[i][j] + b[j];
                if (valid) m = fmaxf(m, lo[j]);
            }
#pragma unroll
            for (int off = 1; off < 16; off <<= 1)
                m = fmaxf(m, __shfl_xor(m, off, 64));
            float s = 0.f;
            if (valid) {
#pragma unroll
                for (int j = 0; j < 4; ++j) s += __expf(lo[j] - m);
            }
#pragma unroll
            for (int off = 1; off < 16; off <<= 1)
                s += __shfl_xor(s, off, 64);
            float lse = __logf(s);
            int ng = base + ty * 4 + i;
            if (ng < n && valid) {
                float4 r;
                r.x = lo[0] - m - lse; r.y = lo[1] - m - lse;
                r.z = lo[2] - m - lse; r.w = lo[3] - m - lse;
                *(float4*)(outp + (size_t)ng * NC + tx * 4) = r;
            }
        }
    }
}

// ---------------- launch ----------------

extern "C" void kernel_launch(void* const* d_in, const int* in_sizes, int n_in,
                              void* d_out, int out_size, void* d_ws, size_t ws_size,
                              hipStream_t stream) {
    const float* x        = (const float*)d_in[0];
    const int*   eidx     = (const int*)d_in[1];
    const float* ew       = (const float*)d_in[2];
    const float* W_in     = (const float*)d_in[3];
    const float* b_in     = (const float*)d_in[4];
    const float* W_layers = (const float*)d_in[5];
    const float* W_out    = (const float*)d_in[6];
    const float* b_out    = (const float*)d_in[7];
    float* out = (float*)d_out;

    const int N = in_sizes[0] / FIN;
    const int E = in_sizes[2];
    const int L = in_sizes[5] / (HD * HD);
    const int* src = eidx;
    const int* dst = eidx + E;

    size_t off = 0;
    auto carve = [&](size_t bytes) {
        void* p = (char*)d_ws + off;
        off += (bytes + 255) & ~(size_t)255;
        return p;
    };
    unsigned long long* packed8 = (unsigned long long*)carve((size_t)N * 8 * 8);
    float*  dinv    = (float*)carve((size_t)N * 4);
    uint2*  cbase   = (uint2*)carve((size_t)N * 8);
    int*    row_ptr = (int*)  carve((size_t)(N + 1) * 4);
    int*    bsums   = (int*)  carve(512 * 4);
    int*    dhist   = (int*)  carve(256 * 4);
    int*    dcursor = (int*)  carve(256 * 4);
    ushort* degc    = (ushort*)carve((size_t)N * 2);
    int*    order   = (int*)  carve((size_t)N * 4);
    float*  Wo_pad  = (float*)carve((size_t)HD * HD * 4);
    float*  bo_pad  = (float*)carve((size_t)HD * 4);
    ushort* Wf      = (ushort*)carve((size_t)FIN * HD * 2);
    ushort* rank    = (ushort*)carve((size_t)E * 2);
    EdgeT*  ed      = (EdgeT*)carve((size_t)E * 8);
    ushort* h0      = (ushort*)carve((size_t)N * HD * 2);
    ushort* hA      = (ushort*)carve((size_t)N * HD * 2);
    ushort* hB      = (ushort*)carve((size_t)N * HD * 2);
    (void)ws_size;

    const int NB = (N + 255) / 256;
    const int EB = (E + 255) / 256;

    initp_kernel<<<(8 * N + 255) / 256, 256, 0, stream>>>(packed8, dhist, N);
    histp_kernel<<<EB, 256, 0, stream>>>(dst, ew, packed8, rank, E, N);
    post_kernel<<<NB, 256, 0, stream>>>(packed8, dinv, cbase, row_ptr, bsums,
                                        degc, dhist, N);
    scan_top_kernel<<<1, 512, 0, stream>>>(bsums, NB);
    scan_add_kernel<<<NB, 256, 0, stream>>>(row_ptr, bsums, N, E);
    binscan_kernel<<<1, 256, 0, stream>>>(dhist, dcursor);
    order_kernel<<<NB, 256, 0, stream>>>(degc, dcursor, order, N);
    scatter_kernel<<<EB, 256, 0, stream>>>(src, dst, ew, dinv, row_ptr, cbase, rank, ed, E);
    setup_kernel<<<(FIN * HD + 255) / 256, 256, 0, stream>>>(W_in, Wf, W_out, b_out,
                                                             Wo_pad, bo_pad);

    projm_kernel<<<(N + 127) / 128, 256, 0, stream>>>(x, Wf, b_in, h0, N);

    const int NT = (N + 63) / 64;
    const int nocts = (N + 7) / 8;
    const int SB = (nocts + 3) / 4;        // 4 waves/block, 1 oct/wave
    const ushort* cur = h0;
    ushort* bufs[2] = { hA, hB };
    for (int i = 0; i < L; ++i) {
        float beta = logf(0.5f / (float)(i + 1) + 1.0f);
        ushort* sup = bufs[i & 1];
        spmm_kernel<<<SB, 256, 0, stream>>>(cur, sup, dinv, row_ptr, ed, order, N);
        lgemm_kernel<1><<<NT, 256, 0, stream>>>(sup, h0, W_layers + (size_t)i * HD * HD,
                                                nullptr, sup, nullptr, N, beta);
        cur = sup;
    }

    lgemm_kernel<2><<<NT, 256, 0, stream>>>(cur, nullptr, Wo_pad, bo_pad, nullptr, out, N, 0.f);
}

// Round 11
// 565.146 us; speedup vs baseline: 1.9223x; 1.9223x over previous
//
#include <hip/hip_runtime.h>
#include <math.h>

#define HD 64
#define FIN 512
#define NC 40

struct __align__(8) EdgeT { int s; float v; };

typedef __attribute__((ext_vector_type(8))) short bf16x8;
typedef __attribute__((ext_vector_type(8))) unsigned short u16x8;
typedef __attribute__((ext_vector_type(4))) float f32x4;

__device__ __forceinline__ float bf2f(ushort u) {
    return __uint_as_float(((unsigned int)u) << 16);
}
__device__ __forceinline__ ushort f2bf(float f) {
    unsigned int u = __float_as_uint(f);
    unsigned int r = (u + 0x7fffu + ((u >> 16) & 1u)) >> 16;   // RNE
    return (ushort)r;
}

// ---------------- graph preprocessing ----------------
// packed8[c*n+i]: bits[48:64) = edge count, bits[0:48) = fixed-point(2^-32) weighted degree.

__global__ __launch_bounds__(256) void initp_kernel(unsigned long long* packed8, int n) {
    int i = blockIdx.x * 256 + threadIdx.x;
    if (i < 8 * n) packed8[i] = (i < n) ? (1ULL << 32) : 0ULL;  // self-loop w=1 in copy 0
}

__global__ __launch_bounds__(256) void histp_kernel(const int* __restrict__ dst,
        const float* __restrict__ w, unsigned long long* packed8,
        ushort* __restrict__ rank, int E, int n) {
    int i = blockIdx.x * 256 + threadIdx.x;
    if (i < E) {
        int d = dst[i];
        int c = i & 7;
        unsigned long long add = (1ULL << 48) |
            (unsigned long long)(w[i] * 4294967296.0f);
        unsigned long long old = atomicAdd(&packed8[(size_t)c * n + d], add);
        rank[i] = (ushort)(old >> 48);
    }
}

// fused: dinv + copy-bases + per-block count scan + per-block degree histogram
// (LDS atomics only — no global atomic hot spots; R10 lesson)
__global__ __launch_bounds__(256) void post_kernel(const unsigned long long* __restrict__ packed8,
        float* __restrict__ dinv, uint2* __restrict__ cbase,
        int* __restrict__ row_ptr, int* __restrict__ bsums,
        ushort* __restrict__ degc, int* __restrict__ blockbins, int n, int nb) {
    __shared__ int s[256];
    __shared__ int hcnt[256];
    const unsigned long long M = 0xFFFFFFFFFFFFULL;
    int t = threadIdx.x;
    int i = blockIdx.x * 256 + t;
    hcnt[t] = 0;
    __syncthreads();
    int cnt = 0;
    if (i < n) {
        int c[8];
        unsigned long long fx = 0;
#pragma unroll
        for (int k = 0; k < 8; ++k) {
            unsigned long long p = packed8[(size_t)k * n + i];
            c[k] = (int)(p >> 48);
            fx += (p & M);
        }
        float deg = (float)((double)fx * (1.0 / 4294967296.0));
        dinv[i] = rsqrtf(deg);                     // deg >= 1 (self-loop)
        int b = 0; uint lo = 0, hi = 0;
#pragma unroll
        for (int k = 0; k < 4; ++k) { lo |= ((uint)b) << (8 * k); b += c[k]; }
#pragma unroll
        for (int k = 0; k < 4; ++k) { hi |= ((uint)b) << (8 * k); b += c[4 + k]; }
        cbase[i] = make_uint2(lo, hi);
        cnt = b;
        int bin = cnt < 255 ? cnt : 255;
        degc[i] = (ushort)bin;
        atomicAdd(&hcnt[bin], 1);                  // LDS atomic
    }
    s[t] = cnt; __syncthreads();
    for (int off = 1; off < 256; off <<= 1) {
        int u = (t >= off) ? s[t - off] : 0;
        __syncthreads();
        s[t] += u;
        __syncthreads();
    }
    if (i < n) row_ptr[i] = s[t] - cnt;
    if (t == 255) bsums[blockIdx.x] = s[255];
    blockbins[t * nb + blockIdx.x] = hcnt[t];      // bin-major for colscan
}

__global__ __launch_bounds__(512) void scan_top_kernel(int* bsums, int nb) {
    __shared__ int s[512];
    int t = threadIdx.x;
    int v = (t < nb) ? bsums[t] : 0;
    s[t] = v; __syncthreads();
    for (int off = 1; off < 512; off <<= 1) {
        int u = (t >= off) ? s[t - off] : 0;
        __syncthreads();
        s[t] += u;
        __syncthreads();
    }
    if (t < nb) bsums[t] = s[t] - v;
}

__global__ __launch_bounds__(256) void scan_add_kernel(int* __restrict__ row_ptr,
        const int* __restrict__ bsums, int n, int E) {
    int i = blockIdx.x * 256 + threadIdx.x;
    if (i < n) row_ptr[i] += bsums[blockIdx.x];
    if (i == 0) row_ptr[n] = E;
}

// per-bin exclusive scan across blocks (one block per bin); nb <= 512
__global__ __launch_bounds__(512) void colscan_kernel(int* __restrict__ blockbins,
        int* __restrict__ binTot, int nb) {
    __shared__ int s[512];
    const int bin = blockIdx.x;
    int t = threadIdx.x;
    int v = (t < nb) ? blockbins[(size_t)bin * nb + t] : 0;
    s[t] = v; __syncthreads();
    for (int off = 1; off < 512; off <<= 1) {
        int u = (t >= off) ? s[t - off] : 0;
        __syncthreads();
        s[t] += u;
        __syncthreads();
    }
    if (t < nb) blockbins[(size_t)bin * nb + t] = s[t] - v;
    if (t == 511) binTot[bin] = s[511];
}

// exclusive scan of 256 bin totals -> dbase
__global__ __launch_bounds__(256) void binbase_kernel(const int* __restrict__ binTot,
        int* __restrict__ dbase) {
    __shared__ int s[256];
    int t = threadIdx.x;
    int v = binTot[t];
    s[t] = v; __syncthreads();
    for (int off = 1; off < 256; off <<= 1) {
        int u = (t >= off) ? s[t - off] : 0;
        __syncthreads();
        s[t] += u;
        __syncthreads();
    }
    dbase[t] = s[t] - v;
}

// stable-ish counting-sort scatter (LDS atomics only; permutation within bin is
// output-invariant: each node's aggregation is identical regardless of wave assignment)
__global__ __launch_bounds__(256) void order2_kernel(const ushort* __restrict__ degc,
        const int* __restrict__ blockbins, const int* __restrict__ dbase,
        int* __restrict__ order, int n, int nb) {
    __shared__ int hcnt[256];
    int t = threadIdx.x;
    int i = blockIdx.x * 256 + t;
    hcnt[t] = 0;
    __syncthreads();
    if (i < n) {
        int bin = degc[i];
        int lrank = atomicAdd(&hcnt[bin], 1);      // LDS atomic
        int pos = dbase[bin] + blockbins[(size_t)bin * nb + blockIdx.x] + lrank;
        order[pos] = i;
    }
}

__global__ __launch_bounds__(256) void scatter_kernel(const int* __restrict__ src,
        const int* __restrict__ dst, const float* __restrict__ w,
        const float* __restrict__ dinv, const int* __restrict__ row_ptr,
        const uint2* __restrict__ cbase, const ushort* __restrict__ rank,
        EdgeT* __restrict__ ed, int E) {
    int i = blockIdx.x * 256 + threadIdx.x;
    if (i < E) {
        int s = src[i], d = dst[i];
        int c = i & 7;
        uint2 cb = cbase[d];
        int base = (int)(((c < 4) ? (cb.x >> (8 * c)) : (cb.y >> (8 * (c - 4)))) & 0xffu);
        int pos = row_ptr[d] + base + (int)rank[i];
        EdgeT e; e.s = s; e.v = dinv[s] * w[i] * dinv[d];
        ed[pos] = e;
    }
}

// setup: W_out zero-pad + b_out pad + W_in -> bf16 fragment-major
__global__ __launch_bounds__(256) void setup_kernel(const float* __restrict__ W,
        ushort* __restrict__ Wf, const float* __restrict__ Wo,
        const float* __restrict__ bo, float* __restrict__ Wo_pad,
        float* __restrict__ bo_pad) {
    int i = blockIdx.x * 256 + threadIdx.x;
    if (i < FIN * HD) {
        int j = i & 7;
        int l = (i >> 3) & 63;
        int t = (i >> 9) & 3;
        int c = i >> 11;
        int k = c * 32 + ((l >> 4) * 8) + j;
        int col = t * 16 + (l & 15);
        Wf[i] = f2bf(W[k * HD + col]);
    }
    if (i < HD * HD) {
        int k = i >> 6, c2 = i & 63;
        Wo_pad[i] = (c2 < NC) ? Wo[k * NC + c2] : 0.f;
    }
    if (i < HD) bo_pad[i] = (i < NC) ? bo[i] : 0.f;
}

// ---------------- SpMM v5 (bf16 h, 8 nodes/wave, degree-sorted): agg = Ahat@h_in ----

__global__ __launch_bounds__(256) void spmm_kernel(const ushort* __restrict__ h_in,
        ushort* __restrict__ agg, const float* __restrict__ dinv,
        const int* __restrict__ row_ptr, const EdgeT* __restrict__ ed,
        const int* __restrict__ order, int n) {
    const int lane = threadIdx.x & 63;
    const int g = lane >> 3;               // node slot 0..7
    const int fl = (lane & 7) * 8;         // feature offset
    int oct = (blockIdx.x * 256 + threadIdx.x) >> 6;
    int idx = oct * 8 + g;
    bool valid = idx < n;
    int node = order[valid ? idx : n - 1];

    float di = dinv[node];
    float sw = di * di;
    u16x8 us = *(const u16x8*)(h_in + (size_t)node * HD + fl);
    float a[8], b[8];
#pragma unroll
    for (int j = 0; j < 8; ++j) { a[j] = sw * bf2f((ushort)us[j]); b[j] = 0.f; }

    int e = row_ptr[node], end = row_ptr[node + 1];
    for (; e + 8 <= end; e += 8) {
        EdgeT Ex[8];
        u16x8 ux[8];
#pragma unroll
        for (int k = 0; k < 8; ++k) Ex[k] = ed[e + k];
#pragma unroll
        for (int k = 0; k < 8; ++k)
            ux[k] = *(const u16x8*)(h_in + (size_t)Ex[k].s * HD + fl);
#pragma unroll
        for (int k = 0; k < 8; k += 2) {
#pragma unroll
            for (int j = 0; j < 8; ++j) {
                a[j] = fmaf(Ex[k].v,     bf2f((ushort)ux[k][j]),     a[j]);
                b[j] = fmaf(Ex[k + 1].v, bf2f((ushort)ux[k + 1][j]), b[j]);
            }
        }
    }
    for (; e + 2 <= end; e += 2) {
        EdgeT E0 = ed[e], E1 = ed[e + 1];
        u16x8 u0 = *(const u16x8*)(h_in + (size_t)E0.s * HD + fl);
        u16x8 u1 = *(const u16x8*)(h_in + (size_t)E1.s * HD + fl);
#pragma unroll
        for (int j = 0; j < 8; ++j) {
            a[j] = fmaf(E0.v, bf2f((ushort)u0[j]), a[j]);
            b[j] = fmaf(E1.v, bf2f((ushort)u1[j]), b[j]);
        }
    }
    if (e < end) {
        EdgeT E0 = ed[e];
        u16x8 u0 = *(const u16x8*)(h_in + (size_t)E0.s * HD + fl);
#pragma unroll
        for (int j = 0; j < 8; ++j) a[j] = fmaf(E0.v, bf2f((ushort)u0[j]), a[j]);
    }

    if (valid) {
        u16x8 r;
#pragma unroll
        for (int j = 0; j < 8; ++j) r[j] = f2bf(a[j] + b[j]);
        *(u16x8*)(agg + (size_t)node * HD + fl) = r;
    }
}

// ---------------- proj (MFMA): h0 = relu(x @ W_in + b_in) -> bf16 ----------------

__global__ __launch_bounds__(256) void projm_kernel(const float* __restrict__ x,
        const ushort* __restrict__ Wf, const float* __restrict__ bias,
        ushort* __restrict__ h0, int n) {
    const int lane = threadIdx.x & 63;
    const int wave = threadIdx.x >> 6;
    const int row = lane & 15;
    const int g = lane >> 4;
    const int base = blockIdx.x * 128 + wave * 32;

    f32x4 acc[2][4];
#pragma unroll
    for (int m = 0; m < 2; ++m)
#pragma unroll
        for (int t = 0; t < 4; ++t) acc[m][t] = (f32x4){0.f, 0.f, 0.f, 0.f};

    for (int c = 0; c < 16; ++c) {
        bf16x8 afr[2];
#pragma unroll
        for (int m = 0; m < 2; ++m) {
            int node = base + m * 16 + row;
            if (node >= n) node = n - 1;
            const float* p = x + (size_t)node * FIN + c * 32 + g * 8;
            float4 v0 = *(const float4*)p;
            float4 v1 = *(const float4*)(p + 4);
            afr[m][0] = (short)f2bf(v0.x); afr[m][1] = (short)f2bf(v0.y);
            afr[m][2] = (short)f2bf(v0.z); afr[m][3] = (short)f2bf(v0.w);
            afr[m][4] = (short)f2bf(v1.x); afr[m][5] = (short)f2bf(v1.y);
            afr[m][6] = (short)f2bf(v1.z); afr[m][7] = (short)f2bf(v1.w);
        }
#pragma unroll
        for (int t = 0; t < 4; ++t) {
            bf16x8 bfr = *(const bf16x8*)(Wf + ((size_t)(c * 4 + t) * 64 + lane) * 8);
            acc[0][t] = __builtin_amdgcn_mfma_f32_16x16x32_bf16(afr[0], bfr, acc[0][t], 0, 0, 0);
            acc[1][t] = __builtin_amdgcn_mfma_f32_16x16x32_bf16(afr[1], bfr, acc[1][t], 0, 0, 0);
        }
    }

    float bj[4];
#pragma unroll
    for (int t = 0; t < 4; ++t) bj[t] = bias[t * 16 + row];
#pragma unroll
    for (int m = 0; m < 2; ++m)
#pragma unroll
        for (int r = 0; r < 4; ++r) {
            int node = base + m * 16 + g * 4 + r;
            if (node < n) {
#pragma unroll
                for (int t = 0; t < 4; ++t) {
                    float v = fmaxf(acc[m][t][r] + bj[t], 0.f);
                    h0[(size_t)node * HD + t * 16 + row] = f2bf(v);
                }
            }
        }
}

// ---------------- layer / output GEMM over bf16 A, fp32 W, K=64 ----------------
// MODE 1: Af = 0.9*agg + 0.1*h0 (f32); C = relu(beta*(Af@W) + (1-beta)*Af) -> bf16
// MODE 2: log_softmax(A@W + bias) over first NC cols -> outp fp32

template<int MODE>
__global__ __launch_bounds__(256) void lgemm_kernel(const ushort* __restrict__ A,
        const ushort* __restrict__ h0r, const float* __restrict__ W,
        const float* __restrict__ bias, ushort* __restrict__ C,
        float* __restrict__ outp, int n, float beta) {
    __shared__ float Af[64 * 68];
    __shared__ float Wl[64 * 64];
    const int tid = threadIdx.x;
    const int tx = tid & 15;
    const int ty = tid >> 4;
    const int base = blockIdx.x * 64;
    const int kq = (tid & 15) * 4;
    const int rw = tid >> 4;

#pragma unroll
    for (int p = 0; p < 4; ++p) {
        int row = rw + p * 16;
        int ng = base + row; if (ng >= n) ng = n - 1;
        ushort4 u = *(const ushort4*)(A + (size_t)ng * HD + kq);
        if constexpr (MODE == 1) {
            ushort4 uh = *(const ushort4*)(h0r + (size_t)ng * HD + kq);
            Af[row * 68 + kq + 0] = fmaf(0.9f, bf2f(u.x), 0.1f * bf2f(uh.x));
            Af[row * 68 + kq + 1] = fmaf(0.9f, bf2f(u.y), 0.1f * bf2f(uh.y));
            Af[row * 68 + kq + 2] = fmaf(0.9f, bf2f(u.z), 0.1f * bf2f(uh.z));
            Af[row * 68 + kq + 3] = fmaf(0.9f, bf2f(u.w), 0.1f * bf2f(uh.w));
        } else {
            Af[row * 68 + kq + 0] = bf2f(u.x);
            Af[row * 68 + kq + 1] = bf2f(u.y);
            Af[row * 68 + kq + 2] = bf2f(u.z);
            Af[row * 68 + kq + 3] = bf2f(u.w);
        }
        *(float4*)(Wl + row * 64 + kq) =
            *(const float4*)(W + (size_t)row * HD + kq);
    }
    __syncthreads();

    float acc[4][4];
#pragma unroll
    for (int i = 0; i < 4; ++i)
#pragma unroll
        for (int j = 0; j < 4; ++j) acc[i][j] = 0.f;

#pragma unroll
    for (int kk = 0; kk < 64; kk += 4) {
        float4 a4[4];
#pragma unroll
        for (int i = 0; i < 4; ++i)
            a4[i] = *(const float4*)(Af + (ty * 4 + i) * 68 + kk);
#pragma unroll
        for (int k2 = 0; k2 < 4; ++k2) {
            float w[4];
            *(float4*)w = *(const float4*)(Wl + (kk + k2) * 64 + tx * 4);
#pragma unroll
            for (int i = 0; i < 4; ++i) {
                float a = ((const float*)&a4[i])[k2];
#pragma unroll
                for (int j = 0; j < 4; ++j) acc[i][j] = fmaf(a, w[j], acc[i][j]);
            }
        }
    }

    if constexpr (MODE == 1) {
        const float ombeta = 1.f - beta;
#pragma unroll
        for (int i = 0; i < 4; ++i) {
            int ng = base + ty * 4 + i;
            if (ng < n) {
                ushort4 r;
                float s0 = Af[(ty * 4 + i) * 68 + tx * 4 + 0];
                float s1 = Af[(ty * 4 + i) * 68 + tx * 4 + 1];
                float s2 = Af[(ty * 4 + i) * 68 + tx * 4 + 2];
                float s3 = Af[(ty * 4 + i) * 68 + tx * 4 + 3];
                r.x = f2bf(fmaxf(fmaf(beta, acc[i][0], ombeta * s0), 0.f));
                r.y = f2bf(fmaxf(fmaf(beta, acc[i][1], ombeta * s1), 0.f));
                r.z = f2bf(fmaxf(fmaf(beta, acc[i][2], ombeta * s2), 0.f));
                r.w = f2bf(fmaxf(fmaf(beta, acc[i][3], ombeta * s3), 0.f));
                *(ushort4*)(C + (size_t)ng * HD + tx * 4) = r;
            }
        }
    } else {
        float b[4];
#pragma unroll
        for (int j = 0; j < 4; ++j) b[j] = bias[tx * 4 + j];
        const bool valid = (tx < 10);
#pragma unroll
        for (int i = 0; i < 4; ++i) {
            float lo[4];
            float m = -3.0e38f;
#pragma unroll
            for (int j = 0; j < 4; ++j) {
                lo[j] = acc[i][j] + b[j];
                if (valid) m = fmaxf(m, lo[j]);
            }
#pragma unroll
            for (int off = 1; off < 16; off <<= 1)
                m = fmaxf(m, __shfl_xor(m, off, 64));
            float s = 0.f;
            if (valid) {
#pragma unroll
                for (int j = 0; j < 4; ++j) s += __expf(lo[j] - m);
            }
#pragma unroll
            for (int off = 1; off < 16; off <<= 1)
                s += __shfl_xor(s, off, 64);
            float lse = __logf(s);
            int ng = base + ty * 4 + i;
            if (ng < n && valid) {
                float4 r;
                r.x = lo[0] - m - lse; r.y = lo[1] - m - lse;
                r.z = lo[2] - m - lse; r.w = lo[3] - m - lse;
                *(float4*)(outp + (size_t)ng * NC + tx * 4) = r;
            }
        }
    }
}

// ---------------- launch ----------------

extern "C" void kernel_launch(void* const* d_in, const int* in_sizes, int n_in,
                              void* d_out, int out_size, void* d_ws, size_t ws_size,
                              hipStream_t stream) {
    const float* x        = (const float*)d_in[0];
    const int*   eidx     = (const int*)d_in[1];
    const float* ew       = (const float*)d_in[2];
    const float* W_in     = (const float*)d_in[3];
    const float* b_in     = (const float*)d_in[4];
    const float* W_layers = (const float*)d_in[5];
    const float* W_out    = (const float*)d_in[6];
    const float* b_out    = (const float*)d_in[7];
    float* out = (float*)d_out;

    const int N = in_sizes[0] / FIN;
    const int E = in_sizes[2];
    const int L = in_sizes[5] / (HD * HD);
    const int* src = eidx;
    const int* dst = eidx + E;

    const int NB = (N + 255) / 256;
    const int EB = (E + 255) / 256;

    size_t off = 0;
    auto carve = [&](size_t bytes) {
        void* p = (char*)d_ws + off;
        off += (bytes + 255) & ~(size_t)255;
        return p;
    };
    unsigned long long* packed8 = (unsigned long long*)carve((size_t)N * 8 * 8);
    float*  dinv     = (float*)carve((size_t)N * 4);
    uint2*  cbase    = (uint2*)carve((size_t)N * 8);
    int*    row_ptr  = (int*)  carve((size_t)(N + 1) * 4);
    int*    bsums    = (int*)  carve(512 * 4);
    int*    blockbins= (int*)  carve((size_t)256 * NB * 4);
    int*    binTot   = (int*)  carve(256 * 4);
    int*    dbase    = (int*)  carve(256 * 4);
    ushort* degc     = (ushort*)carve((size_t)N * 2);
    int*    order    = (int*)  carve((size_t)N * 4);
    float*  Wo_pad   = (float*)carve((size_t)HD * HD * 4);
    float*  bo_pad   = (float*)carve((size_t)HD * 4);
    ushort* Wf       = (ushort*)carve((size_t)FIN * HD * 2);
    ushort* rank     = (ushort*)carve((size_t)E * 2);
    EdgeT*  ed       = (EdgeT*)carve((size_t)E * 8);
    ushort* h0       = (ushort*)carve((size_t)N * HD * 2);
    ushort* hA       = (ushort*)carve((size_t)N * HD * 2);
    ushort* hB       = (ushort*)carve((size_t)N * HD * 2);
    (void)ws_size;

    initp_kernel<<<(8 * N + 255) / 256, 256, 0, stream>>>(packed8, N);
    histp_kernel<<<EB, 256, 0, stream>>>(dst, ew, packed8, rank, E, N);
    post_kernel<<<NB, 256, 0, stream>>>(packed8, dinv, cbase, row_ptr, bsums,
                                        degc, blockbins, N, NB);
    scan_top_kernel<<<1, 512, 0, stream>>>(bsums, NB);
    scan_add_kernel<<<NB, 256, 0, stream>>>(row_ptr, bsums, N, E);
    colscan_kernel<<<256, 512, 0, stream>>>(blockbins, binTot, NB);
    binbase_kernel<<<1, 256, 0, stream>>>(binTot, dbase);
    order2_kernel<<<NB, 256, 0, stream>>>(degc, blockbins, dbase, order, N, NB);
    scatter_kernel<<<EB, 256, 0, stream>>>(src, dst, ew, dinv, row_ptr, cbase, rank, ed, E);
    setup_kernel<<<(FIN * HD + 255) / 256, 256, 0, stream>>>(W_in, Wf, W_out, b_out,
                                                             Wo_pad, bo_pad);

    projm_kernel<<<(N + 127) / 128, 256, 0, stream>>>(x, Wf, b_in, h0, N);

    const int NT = (N + 63) / 64;
    const int nocts = (N + 7) / 8;
    const int SB = (nocts + 3) / 4;        // 4 waves/block, 1 oct/wave
    const ushort* cur = h0;
    ushort* bufs[2] = { hA, hB };
    for (int i = 0; i < L; ++i) {
        float beta = logf(0.5f / (float)(i + 1) + 1.0f);
        ushort* sup = bufs[i & 1];
        spmm_kernel<<<SB, 256, 0, stream>>>(cur, sup, dinv, row_ptr, ed, order, N);
        lgemm_kernel<1><<<NT, 256, 0, stream>>>(sup, h0, W_layers + (size_t)i * HD * HD,
                                                nullptr, sup, nullptr, N, beta);
        cur = sup;
    }

    lgemm_kernel<2><<<NT, 256, 0, stream>>>(cur, nullptr, Wo_pad, bo_pad, nullptr, out, N, 0.f);
}

// Round 12
// 557.986 us; speedup vs baseline: 1.9470x; 1.0128x over previous
//
#include <hip/hip_runtime.h>
#include <math.h>

#define HD 64
#define FIN 512
#define NC 40

struct __align__(8) EdgeT { int s; float v; };

typedef __attribute__((ext_vector_type(8))) short bf16x8;
typedef __attribute__((ext_vector_type(8))) unsigned short u16x8;
typedef __attribute__((ext_vector_type(4))) float f32x4;

__device__ __forceinline__ float bf2f(ushort u) {
    return __uint_as_float(((unsigned int)u) << 16);
}
__device__ __forceinline__ ushort f2bf(float f) {
    unsigned int u = __float_as_uint(f);
    unsigned int r = (u + 0x7fffu + ((u >> 16) & 1u)) >> 16;   // RNE
    return (ushort)r;
}

// ---------------- graph preprocessing ----------------
// packed8[c*n+i]: bits[48:64) = edge count, bits[0:48) = fixed-point(2^-32) weighted degree.
// 8 shadow copies (c = edge_id & 7) cut atomic contention 8x. Fixed-point sum is order-exact.

__global__ __launch_bounds__(256) void initp_kernel(unsigned long long* packed8, int n) {
    int i = blockIdx.x * 256 + threadIdx.x;
    if (i < 8 * n) packed8[i] = (i < n) ? (1ULL << 32) : 0ULL;  // self-loop w=1 in copy 0
}

__global__ __launch_bounds__(256) void histp_kernel(const int* __restrict__ dst,
        const float* __restrict__ w, unsigned long long* packed8,
        ushort* __restrict__ rank, int E, int n) {
    int i = blockIdx.x * 256 + threadIdx.x;
    if (i < E) {
        int d = dst[i];
        int c = i & 7;
        unsigned long long add = (1ULL << 48) |
            (unsigned long long)(w[i] * 4294967296.0f);
        unsigned long long old = atomicAdd(&packed8[(size_t)c * n + d], add);
        rank[i] = (ushort)(old >> 48);
    }
}

// fused: dinv + copy-bases (8 bytes in uint2) + per-block count scan
__global__ __launch_bounds__(256) void post_kernel(const unsigned long long* __restrict__ packed8,
        float* __restrict__ dinv, uint2* __restrict__ cbase,
        int* __restrict__ row_ptr, int* __restrict__ bsums, int n) {
    __shared__ int s[256];
    const unsigned long long M = 0xFFFFFFFFFFFFULL;
    int t = threadIdx.x;
    int i = blockIdx.x * 256 + t;
    int cnt = 0;
    if (i < n) {
        int c[8];
        unsigned long long fx = 0;
#pragma unroll
        for (int k = 0; k < 8; ++k) {
            unsigned long long p = packed8[(size_t)k * n + i];
            c[k] = (int)(p >> 48);
            fx += (p & M);
        }
        float deg = (float)((double)fx * (1.0 / 4294967296.0));
        dinv[i] = rsqrtf(deg);                     // deg >= 1 (self-loop)
        int b = 0; uint lo = 0, hi = 0;
#pragma unroll
        for (int k = 0; k < 4; ++k) { lo |= ((uint)b) << (8 * k); b += c[k]; }
#pragma unroll
        for (int k = 0; k < 4; ++k) { hi |= ((uint)b) << (8 * k); b += c[4 + k]; }
        cbase[i] = make_uint2(lo, hi);
        cnt = b;
    }
    s[t] = cnt; __syncthreads();
    for (int off = 1; off < 256; off <<= 1) {
        int u = (t >= off) ? s[t - off] : 0;
        __syncthreads();
        s[t] += u;
        __syncthreads();
    }
    if (i < n) row_ptr[i] = s[t] - cnt;
    if (t == 255) bsums[blockIdx.x] = s[255];
}

__global__ __launch_bounds__(512) void scan_top_kernel(int* bsums, int nb) {
    __shared__ int s[512];
    int t = threadIdx.x;
    int v = (t < nb) ? bsums[t] : 0;
    s[t] = v; __syncthreads();
    for (int off = 1; off < 512; off <<= 1) {
        int u = (t >= off) ? s[t - off] : 0;
        __syncthreads();
        s[t] += u;
        __syncthreads();
    }
    if (t < nb) bsums[t] = s[t] - v;
}

__global__ __launch_bounds__(256) void scan_add_kernel(int* __restrict__ row_ptr,
        const int* __restrict__ bsums, int n, int E) {
    int i = blockIdx.x * 256 + threadIdx.x;
    if (i < n) row_ptr[i] += bsums[blockIdx.x];
    if (i == 0) row_ptr[n] = E;
}

__global__ __launch_bounds__(256) void scatter_kernel(const int* __restrict__ src,
        const int* __restrict__ dst, const float* __restrict__ w,
        const float* __restrict__ dinv, const int* __restrict__ row_ptr,
        const uint2* __restrict__ cbase, const ushort* __restrict__ rank,
        EdgeT* __restrict__ ed, int E) {
    int i = blockIdx.x * 256 + threadIdx.x;
    if (i < E) {
        int s = src[i], d = dst[i];
        int c = i & 7;
        uint2 cb = cbase[d];
        int base = (int)(((c < 4) ? (cb.x >> (8 * c)) : (cb.y >> (8 * (c - 4)))) & 0xffu);
        int pos = row_ptr[d] + base + (int)rank[i];
        EdgeT e; e.s = s; e.v = dinv[s] * w[i] * dinv[d];
        ed[pos] = e;
    }
}

// setup: W_out zero-pad + b_out pad + W_in -> bf16 fragment-major
// Wf[((c*4+t)*64+l)*8+j] = W_in[c*32+8*(l>>4)+j][t*16+(l&15)]
__global__ __launch_bounds__(256) void setup_kernel(const float* __restrict__ W,
        ushort* __restrict__ Wf, const float* __restrict__ Wo,
        const float* __restrict__ bo, float* __restrict__ Wo_pad,
        float* __restrict__ bo_pad) {
    int i = blockIdx.x * 256 + threadIdx.x;
    if (i < FIN * HD) {
        int j = i & 7;
        int l = (i >> 3) & 63;
        int t = (i >> 9) & 3;
        int c = i >> 11;
        int k = c * 32 + ((l >> 4) * 8) + j;
        int col = t * 16 + (l & 15);
        Wf[i] = f2bf(W[k * HD + col]);
    }
    if (i < HD * HD) {
        int k = i >> 6, c2 = i & 63;
        Wo_pad[i] = (c2 < NC) ? Wo[k * NC + c2] : 0.f;
    }
    if (i < HD) bo_pad[i] = (i < NC) ? bo[i] : 0.f;
}

// ---------------- SpMM v4 (bf16 h, 8 nodes/wave): agg = Ahat @ h_in ----------------
// 8 lanes per node; lane owns feature octet (lane&7)*8 (16B loads). Residual applied
// later in lgemm staging (keeps this latency-bound kernel lean).

__global__ __launch_bounds__(256) void spmm_kernel(const ushort* __restrict__ h_in,
        ushort* __restrict__ agg, const float* __restrict__ dinv,
        const int* __restrict__ row_ptr, const EdgeT* __restrict__ ed, int n) {
    const int lane = threadIdx.x & 63;
    const int g = lane >> 3;               // node slot 0..7
    const int fl = (lane & 7) * 8;         // feature offset
    int oct = (blockIdx.x * 256 + threadIdx.x) >> 6;
    int node = oct * 8 + g;
    bool valid = node < n;
    int nc = valid ? node : n - 1;

    float di = dinv[nc];
    float sw = di * di;
    u16x8 us = *(const u16x8*)(h_in + (size_t)nc * HD + fl);
    float a[8], b[8];
#pragma unroll
    for (int j = 0; j < 8; ++j) { a[j] = sw * bf2f((ushort)us[j]); b[j] = 0.f; }

    int e = row_ptr[nc], end = row_ptr[nc + 1];
    for (; e + 4 <= end; e += 4) {
        EdgeT E0 = ed[e], E1 = ed[e + 1], E2 = ed[e + 2], E3 = ed[e + 3];
        u16x8 u0 = *(const u16x8*)(h_in + (size_t)E0.s * HD + fl);
        u16x8 u1 = *(const u16x8*)(h_in + (size_t)E1.s * HD + fl);
        u16x8 u2 = *(const u16x8*)(h_in + (size_t)E2.s * HD + fl);
        u16x8 u3 = *(const u16x8*)(h_in + (size_t)E3.s * HD + fl);
#pragma unroll
        for (int j = 0; j < 8; ++j) {
            a[j] = fmaf(E0.v, bf2f((ushort)u0[j]), a[j]);
            b[j] = fmaf(E1.v, bf2f((ushort)u1[j]), b[j]);
            a[j] = fmaf(E2.v, bf2f((ushort)u2[j]), a[j]);
            b[j] = fmaf(E3.v, bf2f((ushort)u3[j]), b[j]);
        }
    }
    for (; e < end; ++e) {
        EdgeT E0 = ed[e];
        u16x8 u0 = *(const u16x8*)(h_in + (size_t)E0.s * HD + fl);
#pragma unroll
        for (int j = 0; j < 8; ++j) a[j] = fmaf(E0.v, bf2f((ushort)u0[j]), a[j]);
    }

    if (valid) {
        u16x8 r;
#pragma unroll
        for (int j = 0; j < 8; ++j) r[j] = f2bf(a[j] + b[j]);
        *(u16x8*)(agg + (size_t)node * HD + fl) = r;
    }
}

// ---------------- proj (MFMA): h0 = relu(x @ W_in + b_in) -> bf16 ----------------
// wave: 16 nodes (1 M-frag) x 64 cols (4 N-frags); block = 4 waves = 64 nodes.
// Smaller wave tile -> 2x grid -> ~6 waves/SIMD for latency hiding (R11 post-mortem:
// projm was latency-limited at 3 waves/SIMD, 50us vs 33us x-stream floor).

__global__ __launch_bounds__(256) void projm_kernel(const float* __restrict__ x,
        const ushort* __restrict__ Wf, const float* __restrict__ bias,
        ushort* __restrict__ h0, int n) {
    const int lane = threadIdx.x & 63;
    const int wave = threadIdx.x >> 6;
    const int row = lane & 15;
    const int g = lane >> 4;
    const int base = blockIdx.x * 64 + wave * 16;

    f32x4 acc[4];
#pragma unroll
    for (int t = 0; t < 4; ++t) acc[t] = (f32x4){0.f, 0.f, 0.f, 0.f};

    int nodeA = base + row;
    if (nodeA >= n) nodeA = n - 1;
    const float* xr = x + (size_t)nodeA * FIN + g * 8;

    for (int c = 0; c < 16; ++c) {
        bf16x8 afr;
        float4 v0 = *(const float4*)(xr + c * 32);
        float4 v1 = *(const float4*)(xr + c * 32 + 4);
        afr[0] = (short)f2bf(v0.x); afr[1] = (short)f2bf(v0.y);
        afr[2] = (short)f2bf(v0.z); afr[3] = (short)f2bf(v0.w);
        afr[4] = (short)f2bf(v1.x); afr[5] = (short)f2bf(v1.y);
        afr[6] = (short)f2bf(v1.z); afr[7] = (short)f2bf(v1.w);
#pragma unroll
        for (int t = 0; t < 4; ++t) {
            bf16x8 bfr = *(const bf16x8*)(Wf + ((size_t)(c * 4 + t) * 64 + lane) * 8);
            acc[t] = __builtin_amdgcn_mfma_f32_16x16x32_bf16(afr, bfr, acc[t], 0, 0, 0);
        }
    }

    float bj[4];
#pragma unroll
    for (int t = 0; t < 4; ++t) bj[t] = bias[t * 16 + row];
#pragma unroll
    for (int r = 0; r < 4; ++r) {
        int node = base + g * 4 + r;
        if (node < n) {
#pragma unroll
            for (int t = 0; t < 4; ++t) {
                float v = fmaxf(acc[t][r] + bj[t], 0.f);
                h0[(size_t)node * HD + t * 16 + row] = f2bf(v);
            }
        }
    }
}

// ---------------- layer / output GEMM over bf16 A, fp32 W, K=64 ----------------
// MODE 1: Af = 0.9*agg + 0.1*h0 (f32); C = relu(beta*(Af@W) + (1-beta)*Af) -> bf16
// MODE 2: log_softmax(A@W + bias) over first NC cols -> outp fp32

template<int MODE>
__global__ __launch_bounds__(256) void lgemm_kernel(const ushort* __restrict__ A,
        const ushort* __restrict__ h0r, const float* __restrict__ W,
        const float* __restrict__ bias, ushort* __restrict__ C,
        float* __restrict__ outp, int n, float beta) {
    __shared__ float Af[64 * 68];
    __shared__ float Wl[64 * 64];
    const int tid = threadIdx.x;
    const int tx = tid & 15;
    const int ty = tid >> 4;
    const int base = blockIdx.x * 64;
    const int kq = (tid & 15) * 4;
    const int rw = tid >> 4;

#pragma unroll
    for (int p = 0; p < 4; ++p) {
        int row = rw + p * 16;
        int ng = base + row; if (ng >= n) ng = n - 1;
        ushort4 u = *(const ushort4*)(A + (size_t)ng * HD + kq);
        if constexpr (MODE == 1) {
            ushort4 uh = *(const ushort4*)(h0r + (size_t)ng * HD + kq);
            Af[row * 68 + kq + 0] = fmaf(0.9f, bf2f(u.x), 0.1f * bf2f(uh.x));
            Af[row * 68 + kq + 1] = fmaf(0.9f, bf2f(u.y), 0.1f * bf2f(uh.y));
            Af[row * 68 + kq + 2] = fmaf(0.9f, bf2f(u.z), 0.1f * bf2f(uh.z));
            Af[row * 68 + kq + 3] = fmaf(0.9f, bf2f(u.w), 0.1f * bf2f(uh.w));
        } else {
            Af[row * 68 + kq + 0] = bf2f(u.x);
            Af[row * 68 + kq + 1] = bf2f(u.y);
            Af[row * 68 + kq + 2] = bf2f(u.z);
            Af[row * 68 + kq + 3] = bf2f(u.w);
        }
        *(float4*)(Wl + row * 64 + kq) =
            *(const float4*)(W + (size_t)row * HD + kq);
    }
    __syncthreads();

    float acc[4][4];
#pragma unroll
    for (int i = 0; i < 4; ++i)
#pragma unroll
        for (int j = 0; j < 4; ++j) acc[i][j] = 0.f;

#pragma unroll
    for (int kk = 0; kk < 64; kk += 4) {
        float4 a4[4];
#pragma unroll
        for (int i = 0; i < 4; ++i)
            a4[i] = *(const float4*)(Af + (ty * 4 + i) * 68 + kk);
#pragma unroll
        for (int k2 = 0; k2 < 4; ++k2) {
            float w[4];
            *(float4*)w = *(const float4*)(Wl + (kk + k2) * 64 + tx * 4);
#pragma unroll
            for (int i = 0; i < 4; ++i) {
                float a = ((const float*)&a4[i])[k2];
#pragma unroll
                for (int j = 0; j < 4; ++j) acc[i][j] = fmaf(a, w[j], acc[i][j]);
            }
        }
    }

    if constexpr (MODE == 1) {
        const float ombeta = 1.f - beta;
#pragma unroll
        for (int i = 0; i < 4; ++i) {
            int ng = base + ty * 4 + i;
            if (ng < n) {
                ushort4 r;
                float s0 = Af[(ty * 4 + i) * 68 + tx * 4 + 0];
                float s1 = Af[(ty * 4 + i) * 68 + tx * 4 + 1];
                float s2 = Af[(ty * 4 + i) * 68 + tx * 4 + 2];
                float s3 = Af[(ty * 4 + i) * 68 + tx * 4 + 3];
                r.x = f2bf(fmaxf(fmaf(beta, acc[i][0], ombeta * s0), 0.f));
                r.y = f2bf(fmaxf(fmaf(beta, acc[i][1], ombeta * s1), 0.f));
                r.z = f2bf(fmaxf(fmaf(beta, acc[i][2], ombeta * s2), 0.f));
                r.w = f2bf(fmaxf(fmaf(beta, acc[i][3], ombeta * s3), 0.f));
                *(ushort4*)(C + (size_t)ng * HD + tx * 4) = r;
            }
        }
    } else {
        float b[4];
#pragma unroll
        for (int j = 0; j < 4; ++j) b[j] = bias[tx * 4 + j];
        const bool valid = (tx < 10);
#pragma unroll
        for (int i = 0; i < 4; ++i) {
            float lo[4];
            float m = -3.0e38f;
#pragma unroll
            for (int j = 0; j < 4; ++j) {
                lo[j] = acc[i][j] + b[j];
                if (valid) m = fmaxf(m, lo[j]);
            }
#pragma unroll
            for (int off = 1; off < 16; off <<= 1)
                m = fmaxf(m, __shfl_xor(m, off, 64));
            float s = 0.f;
            if (valid) {
#pragma unroll
                for (int j = 0; j < 4; ++j) s += __expf(lo[j] - m);
            }
#pragma unroll
            for (int off = 1; off < 16; off <<= 1)
                s += __shfl_xor(s, off, 64);
            float lse = __logf(s);
            int ng = base + ty * 4 + i;
            if (ng < n && valid) {
                float4 r;
                r.x = lo[0] - m - lse; r.y = lo[1] - m - lse;
                r.z = lo[2] - m - lse; r.w = lo[3] - m - lse;
                *(float4*)(outp + (size_t)ng * NC + tx * 4) = r;
            }
        }
    }
}

// ---------------- launch ----------------

extern "C" void kernel_launch(void* const* d_in, const int* in_sizes, int n_in,
                              void* d_out, int out_size, void* d_ws, size_t ws_size,
                              hipStream_t stream) {
    const float* x        = (const float*)d_in[0];
    const int*   eidx     = (const int*)d_in[1];
    const float* ew       = (const float*)d_in[2];
    const float* W_in     = (const float*)d_in[3];
    const float* b_in     = (const float*)d_in[4];
    const float* W_layers = (const float*)d_in[5];
    const float* W_out    = (const float*)d_in[6];
    const float* b_out    = (const float*)d_in[7];
    float* out = (float*)d_out;

    const int N = in_sizes[0] / FIN;
    const int E = in_sizes[2];
    const int L = in_sizes[5] / (HD * HD);
    const int* src = eidx;
    const int* dst = eidx + E;

    size_t off = 0;
    auto carve = [&](size_t bytes) {
        void* p = (char*)d_ws + off;
        off += (bytes + 255) & ~(size_t)255;
        return p;
    };
    unsigned long long* packed8 = (unsigned long long*)carve((size_t)N * 8 * 8);
    float*  dinv    = (float*)carve((size_t)N * 4);
    uint2*  cbase   = (uint2*)carve((size_t)N * 8);
    int*    row_ptr = (int*)  carve((size_t)(N + 1) * 4);
    int*    bsums   = (int*)  carve(512 * 4);
    float*  Wo_pad  = (float*)carve((size_t)HD * HD * 4);
    float*  bo_pad  = (float*)carve((size_t)HD * 4);
    ushort* Wf      = (ushort*)carve((size_t)FIN * HD * 2);
    ushort* rank    = (ushort*)carve((size_t)E * 2);
    EdgeT*  ed      = (EdgeT*)carve((size_t)E * 8);
    ushort* h0      = (ushort*)carve((size_t)N * HD * 2);
    ushort* hA      = (ushort*)carve((size_t)N * HD * 2);
    ushort* hB      = (ushort*)carve((size_t)N * HD * 2);
    (void)ws_size;

    const int NB = (N + 255) / 256;
    const int EB = (E + 255) / 256;

    initp_kernel<<<(8 * N + 255) / 256, 256, 0, stream>>>(packed8, N);
    histp_kernel<<<EB, 256, 0, stream>>>(dst, ew, packed8, rank, E, N);
    post_kernel<<<NB, 256, 0, stream>>>(packed8, dinv, cbase, row_ptr, bsums, N);
    scan_top_kernel<<<1, 512, 0, stream>>>(bsums, NB);
    scan_add_kernel<<<NB, 256, 0, stream>>>(row_ptr, bsums, N, E);
    scatter_kernel<<<EB, 256, 0, stream>>>(src, dst, ew, dinv, row_ptr, cbase, rank, ed, E);
    setup_kernel<<<(FIN * HD + 255) / 256, 256, 0, stream>>>(W_in, Wf, W_out, b_out,
                                                             Wo_pad, bo_pad);

    projm_kernel<<<(N + 63) / 64, 256, 0, stream>>>(x, Wf, b_in, h0, N);

    const int NT = (N + 63) / 64;
    const int nocts = (N + 7) / 8;
    const int SB = (nocts + 3) / 4;        // 4 waves/block, 1 oct/wave
    const ushort* cur = h0;
    ushort* bufs[2] = { hA, hB };
    for (int i = 0; i < L; ++i) {
        float beta = logf(0.5f / (float)(i + 1) + 1.0f);
        ushort* sup = bufs[i & 1];
        spmm_kernel<<<SB, 256, 0, stream>>>(cur, sup, dinv, row_ptr, ed, N);
        lgemm_kernel<1><<<NT, 256, 0, stream>>>(sup, h0, W_layers + (size_t)i * HD * HD,
                                                nullptr, sup, nullptr, N, beta);
        cur = sup;
    }

    lgemm_kernel<2><<<NT, 256, 0, stream>>>(cur, nullptr, Wo_pad, bo_pad, nullptr, out, N, 0.f);
}

// Round 13
// 401.533 us; speedup vs baseline: 2.7056x; 1.3896x over previous
//
#include <hip/hip_runtime.h>
#include <math.h>

#define HD 64
#define FIN 512
#define NC 40

struct __align__(8) EdgeT { int s; float v; };

typedef __attribute__((ext_vector_type(8))) short bf16x8;
typedef __attribute__((ext_vector_type(8))) unsigned short u16x8;
typedef __attribute__((ext_vector_type(4))) float f32x4;

__device__ __forceinline__ float bf2f(ushort u) {
    return __uint_as_float(((unsigned int)u) << 16);
}
__device__ __forceinline__ ushort f2bf(float f) {
    unsigned int u = __float_as_uint(f);
    unsigned int r = (u + 0x7fffu + ((u >> 16) & 1u)) >> 16;   // RNE
    return (ushort)r;
}

// ---------------- prep: packed8 init + all weight repacks (1 launch) ----------------
// Wf  [FIN*HD]  : W_in  -> bf16 frag-major (16 K-chunks of 32)
// Wf2 [L*HD*HD] : W_layers -> bf16 frag-major (2 K-chunks of 32)
// frag layout: Wf[((c*4+t)*64+l)*8+j] = W[c*32+8*(l>>4)+j][t*16+(l&15)]

__global__ __launch_bounds__(256) void prep_kernel(unsigned long long* packed8, int n,
        const float* __restrict__ Win, ushort* __restrict__ Wf,
        const float* __restrict__ Wlay, ushort* __restrict__ Wf2, int L,
        const float* __restrict__ Wo, const float* __restrict__ bo,
        float* __restrict__ Wo_pad, float* __restrict__ bo_pad) {
    int i = blockIdx.x * 256 + threadIdx.x;
    if (i < 8 * n) packed8[i] = (i < n) ? (1ULL << 32) : 0ULL;  // self-loop w=1 in copy 0
    if (i < FIN * HD) {
        int j = i & 7, l = (i >> 3) & 63, t = (i >> 9) & 3, c = i >> 11;
        int k = c * 32 + ((l >> 4) * 8) + j;
        Wf[i] = f2bf(Win[k * HD + t * 16 + (l & 15)]);
    }
    if (i < L * HD * HD) {
        int li = i >> 12, ii = i & 4095;
        int j = ii & 7, l = (ii >> 3) & 63, t = (ii >> 9) & 3, c = (ii >> 11) & 1;
        int k = c * 32 + ((l >> 4) * 8) + j;
        Wf2[i] = f2bf(Wlay[(size_t)li * HD * HD + k * HD + t * 16 + (l & 15)]);
    }
    if (i < HD * HD) {
        int k = i >> 6, c2 = i & 63;
        Wo_pad[i] = (c2 < NC) ? Wo[k * NC + c2] : 0.f;
    }
    if (i < HD) bo_pad[i] = (i < NC) ? bo[i] : 0.f;
}

// ---------------- fused: proj (MFMA, blocks < npb) || edge histogram (rest) -------
// Independent work: proj needs only x/Wf/bias; hist needs only edges. Fusing lets the
// atomic-bound hist hide under the MFMA/load-bound proj (R12 post-mortem: they
// serialized for ~90us on one stream).

__global__ __launch_bounds__(256) void histproj_kernel(
        const int* __restrict__ dst, const float* __restrict__ w,
        unsigned long long* packed8, ushort* __restrict__ rank, int E, int n,
        const float* __restrict__ x, const ushort* __restrict__ Wf,
        const float* __restrict__ bias, ushort* __restrict__ h0, int npb) {
    if ((int)blockIdx.x >= npb) {
        int i = (blockIdx.x - npb) * 256 + threadIdx.x;
        if (i < E) {
            int d = dst[i];
            int c = i & 7;
            unsigned long long add = (1ULL << 48) |
                (unsigned long long)(w[i] * 4294967296.0f);
            unsigned long long old = atomicAdd(&packed8[(size_t)c * n + d], add);
            rank[i] = (ushort)(old >> 48);
        }
        return;
    }
    // ---- proj: 16 nodes/wave x 64 cols, 4 waves/block ----
    const int lane = threadIdx.x & 63;
    const int wave = threadIdx.x >> 6;
    const int row = lane & 15;
    const int g = lane >> 4;
    const int base = blockIdx.x * 64 + wave * 16;

    f32x4 acc[4];
#pragma unroll
    for (int t = 0; t < 4; ++t) acc[t] = (f32x4){0.f, 0.f, 0.f, 0.f};

    int nodeA = base + row;
    if (nodeA >= n) nodeA = n - 1;
    const float* xr = x + (size_t)nodeA * FIN + g * 8;

    for (int c = 0; c < 16; ++c) {
        bf16x8 afr;
        float4 v0 = *(const float4*)(xr + c * 32);
        float4 v1 = *(const float4*)(xr + c * 32 + 4);
        afr[0] = (short)f2bf(v0.x); afr[1] = (short)f2bf(v0.y);
        afr[2] = (short)f2bf(v0.z); afr[3] = (short)f2bf(v0.w);
        afr[4] = (short)f2bf(v1.x); afr[5] = (short)f2bf(v1.y);
        afr[6] = (short)f2bf(v1.z); afr[7] = (short)f2bf(v1.w);
#pragma unroll
        for (int t = 0; t < 4; ++t) {
            bf16x8 bfr = *(const bf16x8*)(Wf + ((size_t)(c * 4 + t) * 64 + lane) * 8);
            acc[t] = __builtin_amdgcn_mfma_f32_16x16x32_bf16(afr, bfr, acc[t], 0, 0, 0);
        }
    }

    float bj[4];
#pragma unroll
    for (int t = 0; t < 4; ++t) bj[t] = bias[t * 16 + row];
#pragma unroll
    for (int r = 0; r < 4; ++r) {
        int node = base + g * 4 + r;
        if (node < n) {
#pragma unroll
            for (int t = 0; t < 4; ++t) {
                float v = fmaxf(acc[t][r] + bj[t], 0.f);
                h0[(size_t)node * HD + t * 16 + row] = f2bf(v);
            }
        }
    }
}

// fused: dinv + copy-bases (8 bytes in uint2) + per-block count scan
__global__ __launch_bounds__(256) void post_kernel(const unsigned long long* __restrict__ packed8,
        float* __restrict__ dinv, uint2* __restrict__ cbase,
        int* __restrict__ row_ptr, int* __restrict__ bsums, int n) {
    __shared__ int s[256];
    const unsigned long long M = 0xFFFFFFFFFFFFULL;
    int t = threadIdx.x;
    int i = blockIdx.x * 256 + t;
    int cnt = 0;
    if (i < n) {
        int c[8];
        unsigned long long fx = 0;
#pragma unroll
        for (int k = 0; k < 8; ++k) {
            unsigned long long p = packed8[(size_t)k * n + i];
            c[k] = (int)(p >> 48);
            fx += (p & M);
        }
        float deg = (float)((double)fx * (1.0 / 4294967296.0));
        dinv[i] = rsqrtf(deg);                     // deg >= 1 (self-loop)
        int b = 0; uint lo = 0, hi = 0;
#pragma unroll
        for (int k = 0; k < 4; ++k) { lo |= ((uint)b) << (8 * k); b += c[k]; }
#pragma unroll
        for (int k = 0; k < 4; ++k) { hi |= ((uint)b) << (8 * k); b += c[4 + k]; }
        cbase[i] = make_uint2(lo, hi);
        cnt = b;
    }
    s[t] = cnt; __syncthreads();
    for (int off = 1; off < 256; off <<= 1) {
        int u = (t >= off) ? s[t - off] : 0;
        __syncthreads();
        s[t] += u;
        __syncthreads();
    }
    if (i < n) row_ptr[i] = s[t] - cnt;
    if (t == 255) bsums[blockIdx.x] = s[255];
}

__global__ __launch_bounds__(512) void scan_top_kernel(int* bsums, int nb) {
    __shared__ int s[512];
    int t = threadIdx.x;
    int v = (t < nb) ? bsums[t] : 0;
    s[t] = v; __syncthreads();
    for (int off = 1; off < 512; off <<= 1) {
        int u = (t >= off) ? s[t - off] : 0;
        __syncthreads();
        s[t] += u;
        __syncthreads();
    }
    if (t < nb) bsums[t] = s[t] - v;
}

__global__ __launch_bounds__(256) void scan_add_kernel(int* __restrict__ row_ptr,
        const int* __restrict__ bsums, int n, int E) {
    int i = blockIdx.x * 256 + threadIdx.x;
    if (i < n) row_ptr[i] += bsums[blockIdx.x];
    if (i == 0) row_ptr[n] = E;
}

__global__ __launch_bounds__(256) void scatter_kernel(const int* __restrict__ src,
        const int* __restrict__ dst, const float* __restrict__ w,
        const float* __restrict__ dinv, const int* __restrict__ row_ptr,
        const uint2* __restrict__ cbase, const ushort* __restrict__ rank,
        EdgeT* __restrict__ ed, int E) {
    int i = blockIdx.x * 256 + threadIdx.x;
    if (i < E) {
        int s = src[i], d = dst[i];
        int c = i & 7;
        uint2 cb = cbase[d];
        int base = (int)(((c < 4) ? (cb.x >> (8 * c)) : (cb.y >> (8 * (c - 4)))) & 0xffu);
        int pos = row_ptr[d] + base + (int)rank[i];
        EdgeT e; e.s = s; e.v = dinv[s] * w[i] * dinv[d];
        ed[pos] = e;
    }
}

// ---------------- SpMM v4 (bf16 h, 8 nodes/wave): agg = Ahat @ h_in ----------------

__global__ __launch_bounds__(256) void spmm_kernel(const ushort* __restrict__ h_in,
        ushort* __restrict__ agg, const float* __restrict__ dinv,
        const int* __restrict__ row_ptr, const EdgeT* __restrict__ ed, int n) {
    const int lane = threadIdx.x & 63;
    const int g = lane >> 3;               // node slot 0..7
    const int fl = (lane & 7) * 8;         // feature offset
    int oct = (blockIdx.x * 256 + threadIdx.x) >> 6;
    int node = oct * 8 + g;
    bool valid = node < n;
    int nc = valid ? node : n - 1;

    float di = dinv[nc];
    float sw = di * di;
    u16x8 us = *(const u16x8*)(h_in + (size_t)nc * HD + fl);
    float a[8], b[8];
#pragma unroll
    for (int j = 0; j < 8; ++j) { a[j] = sw * bf2f((ushort)us[j]); b[j] = 0.f; }

    int e = row_ptr[nc], end = row_ptr[nc + 1];
    for (; e + 4 <= end; e += 4) {
        EdgeT E0 = ed[e], E1 = ed[e + 1], E2 = ed[e + 2], E3 = ed[e + 3];
        u16x8 u0 = *(const u16x8*)(h_in + (size_t)E0.s * HD + fl);
        u16x8 u1 = *(const u16x8*)(h_in + (size_t)E1.s * HD + fl);
        u16x8 u2 = *(const u16x8*)(h_in + (size_t)E2.s * HD + fl);
        u16x8 u3 = *(const u16x8*)(h_in + (size_t)E3.s * HD + fl);
#pragma unroll
        for (int j = 0; j < 8; ++j) {
            a[j] = fmaf(E0.v, bf2f((ushort)u0[j]), a[j]);
            b[j] = fmaf(E1.v, bf2f((ushort)u1[j]), b[j]);
            a[j] = fmaf(E2.v, bf2f((ushort)u2[j]), a[j]);
            b[j] = fmaf(E3.v, bf2f((ushort)u3[j]), b[j]);
        }
    }
    for (; e < end; ++e) {
        EdgeT E0 = ed[e];
        u16x8 u0 = *(const u16x8*)(h_in + (size_t)E0.s * HD + fl);
#pragma unroll
        for (int j = 0; j < 8; ++j) a[j] = fmaf(E0.v, bf2f((ushort)u0[j]), a[j]);
    }

    if (valid) {
        u16x8 r;
#pragma unroll
        for (int j = 0; j < 8; ++j) r[j] = f2bf(a[j] + b[j]);
        *(u16x8*)(agg + (size_t)node * HD + fl) = r;
    }
}

// ---------------- layer GEMM (MFMA): C = relu(beta*(sup@W) + (1-beta)*sup) -------
// sup = 0.9*agg + 0.1*h0 computed on the fly (bf16). Wave owns 32 nodes; in-place
// safe: each wave reads only its own rows (A-frags + epilogue) before writing them.

__global__ __launch_bounds__(256) void lgemmm_kernel(const ushort* __restrict__ agg,
        const ushort* __restrict__ h0, const ushort* __restrict__ Wf2,
        ushort* __restrict__ C, int n, float beta) {
    const int lane = threadIdx.x & 63;
    const int wave = threadIdx.x >> 6;
    const int row = lane & 15;
    const int g = lane >> 4;
    const int base = blockIdx.x * 128 + wave * 32;
    const float ombeta = 1.f - beta;

    f32x4 acc[2][4];
#pragma unroll
    for (int m = 0; m < 2; ++m)
#pragma unroll
        for (int t = 0; t < 4; ++t) acc[m][t] = (f32x4){0.f, 0.f, 0.f, 0.f};

    bf16x8 afr[2][2];
#pragma unroll
    for (int m = 0; m < 2; ++m) {
        int node = base + m * 16 + row;
        if (node >= n) node = n - 1;
#pragma unroll
        for (int c = 0; c < 2; ++c) {
            u16x8 ua = *(const u16x8*)(agg + (size_t)node * HD + c * 32 + g * 8);
            u16x8 uh = *(const u16x8*)(h0 + (size_t)node * HD + c * 32 + g * 8);
#pragma unroll
            for (int j = 0; j < 8; ++j)
                afr[m][c][j] = (short)f2bf(fmaf(0.9f, bf2f((ushort)ua[j]),
                                                0.1f * bf2f((ushort)uh[j])));
        }
    }
#pragma unroll
    for (int c = 0; c < 2; ++c) {
#pragma unroll
        for (int t = 0; t < 4; ++t) {
            bf16x8 bfr = *(const bf16x8*)(Wf2 + ((size_t)(c * 4 + t) * 64 + lane) * 8);
            acc[0][t] = __builtin_amdgcn_mfma_f32_16x16x32_bf16(afr[0][c], bfr, acc[0][t], 0, 0, 0);
            acc[1][t] = __builtin_amdgcn_mfma_f32_16x16x32_bf16(afr[1][c], bfr, acc[1][t], 0, 0, 0);
        }
    }

#pragma unroll
    for (int m = 0; m < 2; ++m)
#pragma unroll
        for (int r = 0; r < 4; ++r) {
            int node = base + m * 16 + g * 4 + r;
            if (node < n) {
                ushort rr[4];
#pragma unroll
                for (int t = 0; t < 4; ++t) {
                    int idx = (int)((size_t)0) + t * 16 + row;
                    float sa = bf2f(agg[(size_t)node * HD + idx]);
                    float sh = bf2f(h0[(size_t)node * HD + idx]);
                    float sup = fmaf(0.9f, sa, 0.1f * sh);
                    rr[t] = f2bf(fmaxf(fmaf(beta, acc[m][t][r], ombeta * sup), 0.f));
                }
#pragma unroll
                for (int t = 0; t < 4; ++t)
                    C[(size_t)node * HD + t * 16 + row] = rr[t];
            }
        }
}

// ---------------- output GEMM + log_softmax (bf16 A, fp32 W, K=64) ----------------

__global__ __launch_bounds__(256) void outg_kernel(const ushort* __restrict__ A,
        const float* __restrict__ W, const float* __restrict__ bias,
        float* __restrict__ outp, int n) {
    __shared__ float Af[64 * 68];
    __shared__ float Wl[64 * 64];
    const int tid = threadIdx.x;
    const int tx = tid & 15;
    const int ty = tid >> 4;
    const int base = blockIdx.x * 64;
    const int kq = (tid & 15) * 4;
    const int rw = tid >> 4;

#pragma unroll
    for (int p = 0; p < 4; ++p) {
        int row = rw + p * 16;
        int ng = base + row; if (ng >= n) ng = n - 1;
        ushort4 u = *(const ushort4*)(A + (size_t)ng * HD + kq);
        Af[row * 68 + kq + 0] = bf2f(u.x);
        Af[row * 68 + kq + 1] = bf2f(u.y);
        Af[row * 68 + kq + 2] = bf2f(u.z);
        Af[row * 68 + kq + 3] = bf2f(u.w);
        *(float4*)(Wl + row * 64 + kq) =
            *(const float4*)(W + (size_t)row * HD + kq);
    }
    __syncthreads();

    float acc[4][4];
#pragma unroll
    for (int i = 0; i < 4; ++i)
#pragma unroll
        for (int j = 0; j < 4; ++j) acc[i][j] = 0.f;

#pragma unroll
    for (int kk = 0; kk < 64; kk += 4) {
        float4 a4[4];
#pragma unroll
        for (int i = 0; i < 4; ++i)
            a4[i] = *(const float4*)(Af + (ty * 4 + i) * 68 + kk);
#pragma unroll
        for (int k2 = 0; k2 < 4; ++k2) {
            float w[4];
            *(float4*)w = *(const float4*)(Wl + (kk + k2) * 64 + tx * 4);
#pragma unroll
            for (int i = 0; i < 4; ++i) {
                float a = ((const float*)&a4[i])[k2];
#pragma unroll
                for (int j = 0; j < 4; ++j) acc[i][j] = fmaf(a, w[j], acc[i][j]);
            }
        }
    }

    float b[4];
#pragma unroll
    for (int j = 0; j < 4; ++j) b[j] = bias[tx * 4 + j];
    const bool valid = (tx < 10);
#pragma unroll
    for (int i = 0; i < 4; ++i) {
        float lo[4];
        float m = -3.0e38f;
#pragma unroll
        for (int j = 0; j < 4; ++j) {
            lo[j] = acc[i][j] + b[j];
            if (valid) m = fmaxf(m, lo[j]);
        }
#pragma unroll
        for (int off = 1; off < 16; off <<= 1)
            m = fmaxf(m, __shfl_xor(m, off, 64));
        float s = 0.f;
        if (valid) {
#pragma unroll
            for (int j = 0; j < 4; ++j) s += __expf(lo[j] - m);
        }
#pragma unroll
        for (int off = 1; off < 16; off <<= 1)
            s += __shfl_xor(s, off, 64);
        float lse = __logf(s);
        int ng = base + ty * 4 + i;
        if (ng < n && valid) {
            float4 r;
            r.x = lo[0] - m - lse; r.y = lo[1] - m - lse;
            r.z = lo[2] - m - lse; r.w = lo[3] - m - lse;
            *(float4*)(outp + (size_t)ng * NC + tx * 4) = r;
        }
    }
}

// ---------------- launch ----------------

extern "C" void kernel_launch(void* const* d_in, const int* in_sizes, int n_in,
                              void* d_out, int out_size, void* d_ws, size_t ws_size,
                              hipStream_t stream) {
    const float* x        = (const float*)d_in[0];
    const int*   eidx     = (const int*)d_in[1];
    const float* ew       = (const float*)d_in[2];
    const float* W_in     = (const float*)d_in[3];
    const float* b_in     = (const float*)d_in[4];
    const float* W_layers = (const float*)d_in[5];
    const float* W_out    = (const float*)d_in[6];
    const float* b_out    = (const float*)d_in[7];
    float* out = (float*)d_out;

    const int N = in_sizes[0] / FIN;
    const int E = in_sizes[2];
    const int L = in_sizes[5] / (HD * HD);
    const int* src = eidx;
    const int* dst = eidx + E;

    size_t off = 0;
    auto carve = [&](size_t bytes) {
        void* p = (char*)d_ws + off;
        off += (bytes + 255) & ~(size_t)255;
        return p;
    };
    unsigned long long* packed8 = (unsigned long long*)carve((size_t)N * 8 * 8);
    float*  dinv    = (float*)carve((size_t)N * 4);
    uint2*  cbase   = (uint2*)carve((size_t)N * 8);
    int*    row_ptr = (int*)  carve((size_t)(N + 1) * 4);
    int*    bsums   = (int*)  carve(512 * 4);
    float*  Wo_pad  = (float*)carve((size_t)HD * HD * 4);
    float*  bo_pad  = (float*)carve((size_t)HD * 4);
    ushort* Wf      = (ushort*)carve((size_t)FIN * HD * 2);
    ushort* Wf2     = (ushort*)carve((size_t)L * HD * HD * 2);
    ushort* rank    = (ushort*)carve((size_t)E * 2);
    EdgeT*  ed      = (EdgeT*)carve((size_t)E * 8);
    ushort* h0      = (ushort*)carve((size_t)N * HD * 2);
    ushort* hA      = (ushort*)carve((size_t)N * HD * 2);
    ushort* hB      = (ushort*)carve((size_t)N * HD * 2);
    (void)ws_size;

    const int NB = (N + 255) / 256;
    const int EB = (E + 255) / 256;
    const int NPB = (N + 63) / 64;         // proj blocks

    prep_kernel<<<(8 * N + 255) / 256, 256, 0, stream>>>(packed8, N, W_in, Wf,
                                                         W_layers, Wf2, L,
                                                         W_out, b_out, Wo_pad, bo_pad);
    histproj_kernel<<<NPB + EB, 256, 0, stream>>>(dst, ew, packed8, rank, E, N,
                                                  x, Wf, b_in, h0, NPB);
    post_kernel<<<NB, 256, 0, stream>>>(packed8, dinv, cbase, row_ptr, bsums, N);
    scan_top_kernel<<<1, 512, 0, stream>>>(bsums, NB);
    scan_add_kernel<<<NB, 256, 0, stream>>>(row_ptr, bsums, N, E);
    scatter_kernel<<<EB, 256, 0, stream>>>(src, dst, ew, dinv, row_ptr, cbase, rank, ed, E);

    const int nocts = (N + 7) / 8;
    const int SB = (nocts + 3) / 4;        // 4 waves/block, 1 oct/wave
    const int LB = (N + 127) / 128;        // lgemmm blocks
    const ushort* cur = h0;
    ushort* bufs[2] = { hA, hB };
    for (int i = 0; i < L; ++i) {
        float beta = logf(0.5f / (float)(i + 1) + 1.0f);
        ushort* sup = bufs[i & 1];
        spmm_kernel<<<SB, 256, 0, stream>>>(cur, sup, dinv, row_ptr, ed, N);
        lgemmm_kernel<<<LB, 256, 0, stream>>>(sup, h0, Wf2 + (size_t)i * HD * HD,
                                              sup, N, beta);
        cur = sup;
    }

    outg_kernel<<<(N + 63) / 64, 256, 0, stream>>>(cur, Wo_pad, bo_pad, out, N);
}

// Round 14
// 348.310 us; speedup vs baseline: 3.1190x; 1.1528x over previous
//
#include <hip/hip_runtime.h>
#include <math.h>

#define HD 64
#define FIN 512
#define NC 40

struct __align__(8) EdgeT { int s; float v; };

typedef __attribute__((ext_vector_type(8))) short bf16x8;
typedef __attribute__((ext_vector_type(8))) unsigned short u16x8;
typedef __attribute__((ext_vector_type(4))) float f32x4;

__device__ __forceinline__ float bf2f(ushort u) {
    return __uint_as_float(((unsigned int)u) << 16);
}
__device__ __forceinline__ ushort f2bf(float f) {
    unsigned int u = __float_as_uint(f);
    unsigned int r = (u + 0x7fffu + ((u >> 16) & 1u)) >> 16;   // RNE
    return (ushort)r;
}

// ---------------- prep: packed8 init + all weight repacks (1 launch) ----------------
// frag layout: Wf[((c*4+t)*64+l)*8+j] = W[c*32+8*(l>>4)+j][t*16+(l&15)]

__global__ __launch_bounds__(256) void prep_kernel(unsigned long long* packed8, int n,
        const float* __restrict__ Win, ushort* __restrict__ Wf,
        const float* __restrict__ Wlay, ushort* __restrict__ Wf2, int L,
        const float* __restrict__ Wo, const float* __restrict__ bo,
        ushort* __restrict__ Wfo, float* __restrict__ bo_pad) {
    int i = blockIdx.x * 256 + threadIdx.x;
    if (i < 8 * n) packed8[i] = (i < n) ? (1ULL << 32) : 0ULL;  // self-loop w=1 in copy 0
    if (i < FIN * HD) {
        int j = i & 7, l = (i >> 3) & 63, t = (i >> 9) & 3, c = i >> 11;
        int k = c * 32 + ((l >> 4) * 8) + j;
        Wf[i] = f2bf(Win[k * HD + t * 16 + (l & 15)]);
    }
    if (i < L * HD * HD) {
        int li = i >> 12, ii = i & 4095;
        int j = ii & 7, l = (ii >> 3) & 63, t = (ii >> 9) & 3, c = (ii >> 11) & 1;
        int k = c * 32 + ((l >> 4) * 8) + j;
        Wf2[i] = f2bf(Wlay[(size_t)li * HD * HD + k * HD + t * 16 + (l & 15)]);
    }
    if (i < HD * HD) {   // 4096 = 2 c-chunks * 4 t * 64 l * 8 j
        int j = i & 7, l = (i >> 3) & 63, t = (i >> 9) & 3, c = (i >> 11) & 1;
        int k = c * 32 + ((l >> 4) * 8) + j;
        int col = t * 16 + (l & 15);
        Wfo[i] = (col < NC) ? f2bf(Wo[k * NC + col]) : (ushort)0;
    }
    if (i < HD) bo_pad[i] = (i < NC) ? bo[i] : 0.f;
}

// ---------------- fused: proj (MFMA, blocks < npb) || edge histogram (rest) -------

__global__ __launch_bounds__(256) void histproj_kernel(
        const int* __restrict__ dst, const float* __restrict__ w,
        unsigned long long* packed8, ushort* __restrict__ rank, int E, int n,
        const float* __restrict__ x, const ushort* __restrict__ Wf,
        const float* __restrict__ bias, ushort* __restrict__ h0, int npb) {
    if ((int)blockIdx.x >= npb) {
        int i = (blockIdx.x - npb) * 256 + threadIdx.x;
        if (i < E) {
            int d = dst[i];
            int c = i & 7;
            unsigned long long add = (1ULL << 48) |
                (unsigned long long)(w[i] * 4294967296.0f);
            unsigned long long old = atomicAdd(&packed8[(size_t)c * n + d], add);
            rank[i] = (ushort)(old >> 48);
        }
        return;
    }
    const int lane = threadIdx.x & 63;
    const int wave = threadIdx.x >> 6;
    const int row = lane & 15;
    const int g = lane >> 4;
    const int base = blockIdx.x * 64 + wave * 16;

    f32x4 acc[4];
#pragma unroll
    for (int t = 0; t < 4; ++t) acc[t] = (f32x4){0.f, 0.f, 0.f, 0.f};

    int nodeA = base + row;
    if (nodeA >= n) nodeA = n - 1;
    const float* xr = x + (size_t)nodeA * FIN + g * 8;

    for (int c = 0; c < 16; ++c) {
        bf16x8 afr;
        float4 v0 = *(const float4*)(xr + c * 32);
        float4 v1 = *(const float4*)(xr + c * 32 + 4);
        afr[0] = (short)f2bf(v0.x); afr[1] = (short)f2bf(v0.y);
        afr[2] = (short)f2bf(v0.z); afr[3] = (short)f2bf(v0.w);
        afr[4] = (short)f2bf(v1.x); afr[5] = (short)f2bf(v1.y);
        afr[6] = (short)f2bf(v1.z); afr[7] = (short)f2bf(v1.w);
#pragma unroll
        for (int t = 0; t < 4; ++t) {
            bf16x8 bfr = *(const bf16x8*)(Wf + ((size_t)(c * 4 + t) * 64 + lane) * 8);
            acc[t] = __builtin_amdgcn_mfma_f32_16x16x32_bf16(afr, bfr, acc[t], 0, 0, 0);
        }
    }

    float bj[4];
#pragma unroll
    for (int t = 0; t < 4; ++t) bj[t] = bias[t * 16 + row];
#pragma unroll
    for (int r = 0; r < 4; ++r) {
        int node = base + g * 4 + r;
        if (node < n) {
#pragma unroll
            for (int t = 0; t < 4; ++t) {
                float v = fmaxf(acc[t][r] + bj[t], 0.f);
                h0[(size_t)node * HD + t * 16 + row] = f2bf(v);
            }
        }
    }
}

// fused: dinv + copy-bases (8 bytes in uint2) + per-block count scan
__global__ __launch_bounds__(256) void post_kernel(const unsigned long long* __restrict__ packed8,
        float* __restrict__ dinv, uint2* __restrict__ cbase,
        int* __restrict__ row_ptr, int* __restrict__ bsums, int n) {
    __shared__ int s[256];
    const unsigned long long M = 0xFFFFFFFFFFFFULL;
    int t = threadIdx.x;
    int i = blockIdx.x * 256 + t;
    int cnt = 0;
    if (i < n) {
        int c[8];
        unsigned long long fx = 0;
#pragma unroll
        for (int k = 0; k < 8; ++k) {
            unsigned long long p = packed8[(size_t)k * n + i];
            c[k] = (int)(p >> 48);
            fx += (p & M);
        }
        float deg = (float)((double)fx * (1.0 / 4294967296.0));
        dinv[i] = rsqrtf(deg);                     // deg >= 1 (self-loop)
        int b = 0; uint lo = 0, hi = 0;
#pragma unroll
        for (int k = 0; k < 4; ++k) { lo |= ((uint)b) << (8 * k); b += c[k]; }
#pragma unroll
        for (int k = 0; k < 4; ++k) { hi |= ((uint)b) << (8 * k); b += c[4 + k]; }
        cbase[i] = make_uint2(lo, hi);
        cnt = b;
    }
    s[t] = cnt; __syncthreads();
    for (int off = 1; off < 256; off <<= 1) {
        int u = (t >= off) ? s[t - off] : 0;
        __syncthreads();
        s[t] += u;
        __syncthreads();
    }
    if (i < n) row_ptr[i] = s[t] - cnt;
    if (t == 255) bsums[blockIdx.x] = s[255];
}

__global__ __launch_bounds__(512) void scan_top_kernel(int* bsums, int nb) {
    __shared__ int s[512];
    int t = threadIdx.x;
    int v = (t < nb) ? bsums[t] : 0;
    s[t] = v; __syncthreads();
    for (int off = 1; off < 512; off <<= 1) {
        int u = (t >= off) ? s[t - off] : 0;
        __syncthreads();
        s[t] += u;
        __syncthreads();
    }
    if (t < nb) bsums[t] = s[t] - v;
}

__global__ __launch_bounds__(256) void scan_add_kernel(int* __restrict__ row_ptr,
        const int* __restrict__ bsums, int n, int E) {
    int i = blockIdx.x * 256 + threadIdx.x;
    if (i < n) row_ptr[i] += bsums[blockIdx.x];
    if (i == 0) row_ptr[n] = E;
}

__global__ __launch_bounds__(256) void scatter_kernel(const int* __restrict__ src,
        const int* __restrict__ dst, const float* __restrict__ w,
        const float* __restrict__ dinv, const int* __restrict__ row_ptr,
        const uint2* __restrict__ cbase, const ushort* __restrict__ rank,
        EdgeT* __restrict__ ed, int E) {
    int i = blockIdx.x * 256 + threadIdx.x;
    if (i < E) {
        int s = src[i], d = dst[i];
        int c = i & 7;
        uint2 cb = cbase[d];
        int base = (int)(((c < 4) ? (cb.x >> (8 * c)) : (cb.y >> (8 * (c - 4)))) & 0xffu);
        int pos = row_ptr[d] + base + (int)rank[i];
        EdgeT e; e.s = s; e.v = dinv[s] * w[i] * dinv[d];
        ed[pos] = e;
    }
}

// ---------------- fused layer: gather(spmm) + MFMA GEMM + residual + relu --------
// Wave-autonomous 32-node tile: 4 gather passes (8 nodes, 8 lanes/node, 16B loads),
// sup -> bf16 in private LDS slice; wave-local barrier; 16 MFMA; epilogue.
// Lean VGPR (R7 lesson); LDS stride 72 ushorts -> 2-way banks (free).

__global__ __launch_bounds__(256) void layerm_kernel(const ushort* __restrict__ h_in,
        const ushort* __restrict__ h0, ushort* __restrict__ h_out,
        const ushort* __restrict__ Wf2, const float* __restrict__ dinv,
        const int* __restrict__ row_ptr, const EdgeT* __restrict__ ed,
        float beta, int n) {
    __shared__ ushort S[4][32 * 72];       // 18.4 KB
    const int lane = threadIdx.x & 63;
    const int wave = threadIdx.x >> 6;
    ushort* Sw = S[wave];
    const int wbase = (blockIdx.x * 4 + wave) * 32;
    const int gs = lane >> 3;              // node slot 0..7
    const int fl = (lane & 7) * 8;         // feature offset

#pragma unroll
    for (int p = 0; p < 4; ++p) {
        int node = wbase + p * 8 + gs;
        int nc = (node < n) ? node : n - 1;
        float di = dinv[nc];
        float sw = di * di;
        u16x8 us = *(const u16x8*)(h_in + (size_t)nc * HD + fl);
        float a[8], b[8];
#pragma unroll
        for (int j = 0; j < 8; ++j) { a[j] = sw * bf2f((ushort)us[j]); b[j] = 0.f; }

        int e = row_ptr[nc], end = row_ptr[nc + 1];
        for (; e + 4 <= end; e += 4) {
            EdgeT E0 = ed[e], E1 = ed[e + 1], E2 = ed[e + 2], E3 = ed[e + 3];
            u16x8 u0 = *(const u16x8*)(h_in + (size_t)E0.s * HD + fl);
            u16x8 u1 = *(const u16x8*)(h_in + (size_t)E1.s * HD + fl);
            u16x8 u2 = *(const u16x8*)(h_in + (size_t)E2.s * HD + fl);
            u16x8 u3 = *(const u16x8*)(h_in + (size_t)E3.s * HD + fl);
#pragma unroll
            for (int j = 0; j < 8; ++j) {
                a[j] = fmaf(E0.v, bf2f((ushort)u0[j]), a[j]);
                b[j] = fmaf(E1.v, bf2f((ushort)u1[j]), b[j]);
                a[j] = fmaf(E2.v, bf2f((ushort)u2[j]), a[j]);
                b[j] = fmaf(E3.v, bf2f((ushort)u3[j]), b[j]);
            }
        }
        for (; e < end; ++e) {
            EdgeT E0 = ed[e];
            u16x8 u0 = *(const u16x8*)(h_in + (size_t)E0.s * HD + fl);
#pragma unroll
            for (int j = 0; j < 8; ++j) a[j] = fmaf(E0.v, bf2f((ushort)u0[j]), a[j]);
        }

        u16x8 uh = *(const u16x8*)(h0 + (size_t)nc * HD + fl);
        u16x8 r;
#pragma unroll
        for (int j = 0; j < 8; ++j)
            r[j] = f2bf(fmaf(0.9f, a[j] + b[j], 0.1f * bf2f((ushort)uh[j])));
        *(u16x8*)(Sw + (p * 8 + gs) * 72 + fl) = r;
    }

    asm volatile("s_waitcnt lgkmcnt(0)" ::: "memory");
    __builtin_amdgcn_wave_barrier();
    __builtin_amdgcn_sched_barrier(0);

    // ---- MFMA: 32 nodes x 64 cols ----
    const int row = lane & 15;
    const int g = lane >> 4;
    f32x4 acc[2][4];
#pragma unroll
    for (int m = 0; m < 2; ++m)
#pragma unroll
        for (int t = 0; t < 4; ++t) acc[m][t] = (f32x4){0.f, 0.f, 0.f, 0.f};

#pragma unroll
    for (int c = 0; c < 2; ++c) {
        bf16x8 afr[2];
#pragma unroll
        for (int m = 0; m < 2; ++m)
            afr[m] = *(const bf16x8*)(Sw + (m * 16 + row) * 72 + c * 32 + g * 8);
#pragma unroll
        for (int t = 0; t < 4; ++t) {
            bf16x8 bfr = *(const bf16x8*)(Wf2 + ((size_t)(c * 4 + t) * 64 + lane) * 8);
            acc[0][t] = __builtin_amdgcn_mfma_f32_16x16x32_bf16(afr[0], bfr, acc[0][t], 0, 0, 0);
            acc[1][t] = __builtin_amdgcn_mfma_f32_16x16x32_bf16(afr[1], bfr, acc[1][t], 0, 0, 0);
        }
    }

    const float ombeta = 1.f - beta;
#pragma unroll
    for (int m = 0; m < 2; ++m)
#pragma unroll
        for (int r = 0; r < 4; ++r) {
            int node = wbase + m * 16 + g * 4 + r;
            if (node < n) {
#pragma unroll
                for (int t = 0; t < 4; ++t) {
                    float sup = bf2f(Sw[(m * 16 + g * 4 + r) * 72 + t * 16 + row]);
                    float v = fmaxf(fmaf(beta, acc[m][t][r], ombeta * sup), 0.f);
                    h_out[(size_t)node * HD + t * 16 + row] = f2bf(v);
                }
            }
        }
}

// ---------------- output (MFMA) + log_softmax: out = lsm(h @ W_out + b) ----------
// A-frags straight from global bf16 (reinterpret). Reductions in 16-lane groups
// (xor 1,2,4,8 keeps g fixed). col = t*16+row, valid < NC.

__global__ __launch_bounds__(256) void outm_kernel(const ushort* __restrict__ A,
        const ushort* __restrict__ Wfo, const float* __restrict__ bo_pad,
        float* __restrict__ outp, int n) {
    const int lane = threadIdx.x & 63;
    const int wave = threadIdx.x >> 6;
    const int row = lane & 15;
    const int g = lane >> 4;
    const int base = blockIdx.x * 128 + wave * 32;

    f32x4 acc[2][4];
#pragma unroll
    for (int m = 0; m < 2; ++m)
#pragma unroll
        for (int t = 0; t < 4; ++t) acc[m][t] = (f32x4){0.f, 0.f, 0.f, 0.f};

#pragma unroll
    for (int c = 0; c < 2; ++c) {
        bf16x8 afr[2];
#pragma unroll
        for (int m = 0; m < 2; ++m) {
            int node = base + m * 16 + row;
            if (node >= n) node = n - 1;
            afr[m] = *(const bf16x8*)(A + (size_t)node * HD + c * 32 + g * 8);
        }
#pragma unroll
        for (int t = 0; t < 4; ++t) {
            bf16x8 bfr = *(const bf16x8*)(Wfo + ((size_t)(c * 4 + t) * 64 + lane) * 8);
            acc[0][t] = __builtin_amdgcn_mfma_f32_16x16x32_bf16(afr[0], bfr, acc[0][t], 0, 0, 0);
            acc[1][t] = __builtin_amdgcn_mfma_f32_16x16x32_bf16(afr[1], bfr, acc[1][t], 0, 0, 0);
        }
    }

    float bj[4];
#pragma unroll
    for (int t = 0; t < 4; ++t) bj[t] = bo_pad[t * 16 + row];
    const bool v2 = (row < 8);             // col = 32+row < 40
#pragma unroll
    for (int m = 0; m < 2; ++m)
#pragma unroll
        for (int r = 0; r < 4; ++r) {
            float lo[3];
            lo[0] = acc[m][0][r] + bj[0];
            lo[1] = acc[m][1][r] + bj[1];
            lo[2] = acc[m][2][r] + bj[2];
            float mx = fmaxf(lo[0], lo[1]);
            if (v2) mx = fmaxf(mx, lo[2]);
#pragma unroll
            for (int off = 1; off < 16; off <<= 1)
                mx = fmaxf(mx, __shfl_xor(mx, off, 64));
            float s = __expf(lo[0] - mx) + __expf(lo[1] - mx);
            if (v2) s += __expf(lo[2] - mx);
#pragma unroll
            for (int off = 1; off < 16; off <<= 1)
                s += __shfl_xor(s, off, 64);
            float lse = __logf(s);
            int node = base + m * 16 + g * 4 + r;
            if (node < n) {
                outp[(size_t)node * NC + row] = lo[0] - mx - lse;
                outp[(size_t)node * NC + 16 + row] = lo[1] - mx - lse;
                if (v2) outp[(size_t)node * NC + 32 + row] = lo[2] - mx - lse;
            }
        }
}

// ---------------- launch ----------------

extern "C" void kernel_launch(void* const* d_in, const int* in_sizes, int n_in,
                              void* d_out, int out_size, void* d_ws, size_t ws_size,
                              hipStream_t stream) {
    const float* x        = (const float*)d_in[0];
    const int*   eidx     = (const int*)d_in[1];
    const float* ew       = (const float*)d_in[2];
    const float* W_in     = (const float*)d_in[3];
    const float* b_in     = (const float*)d_in[4];
    const float* W_layers = (const float*)d_in[5];
    const float* W_out    = (const float*)d_in[6];
    const float* b_out    = (const float*)d_in[7];
    float* out = (float*)d_out;

    const int N = in_sizes[0] / FIN;
    const int E = in_sizes[2];
    const int L = in_sizes[5] / (HD * HD);
    const int* src = eidx;
    const int* dst = eidx + E;

    size_t off = 0;
    auto carve = [&](size_t bytes) {
        void* p = (char*)d_ws + off;
        off += (bytes + 255) & ~(size_t)255;
        return p;
    };
    unsigned long long* packed8 = (unsigned long long*)carve((size_t)N * 8 * 8);
    float*  dinv    = (float*)carve((size_t)N * 4);
    uint2*  cbase   = (uint2*)carve((size_t)N * 8);
    int*    row_ptr = (int*)  carve((size_t)(N + 1) * 4);
    int*    bsums   = (int*)  carve(512 * 4);
    float*  bo_pad  = (float*)carve((size_t)HD * 4);
    ushort* Wf      = (ushort*)carve((size_t)FIN * HD * 2);
    ushort* Wf2     = (ushort*)carve((size_t)L * HD * HD * 2);
    ushort* Wfo     = (ushort*)carve((size_t)HD * HD * 2);
    ushort* rank    = (ushort*)carve((size_t)E * 2);
    EdgeT*  ed      = (EdgeT*)carve((size_t)E * 8);
    ushort* h0      = (ushort*)carve((size_t)N * HD * 2);
    ushort* hA      = (ushort*)carve((size_t)N * HD * 2);
    ushort* hB      = (ushort*)carve((size_t)N * HD * 2);
    (void)ws_size;

    const int NB = (N + 255) / 256;
    const int EB = (E + 255) / 256;
    const int NPB = (N + 63) / 64;         // proj blocks

    prep_kernel<<<(8 * N + 255) / 256, 256, 0, stream>>>(packed8, N, W_in, Wf,
                                                         W_layers, Wf2, L,
                                                         W_out, b_out, Wfo, bo_pad);
    histproj_kernel<<<NPB + EB, 256, 0, stream>>>(dst, ew, packed8, rank, E, N,
                                                  x, Wf, b_in, h0, NPB);
    post_kernel<<<NB, 256, 0, stream>>>(packed8, dinv, cbase, row_ptr, bsums, N);
    scan_top_kernel<<<1, 512, 0, stream>>>(bsums, NB);
    scan_add_kernel<<<NB, 256, 0, stream>>>(row_ptr, bsums, N, E);
    scatter_kernel<<<EB, 256, 0, stream>>>(src, dst, ew, dinv, row_ptr, cbase, rank, ed, E);

    const int LB = (N + 127) / 128;        // 4 waves x 32 nodes
    const ushort* cur = h0;
    ushort* bufs[2] = { hA, hB };
    for (int i = 0; i < L; ++i) {
        float beta = logf(0.5f / (float)(i + 1) + 1.0f);
        ushort* nxt = bufs[i & 1];
        layerm_kernel<<<LB, 256, 0, stream>>>(cur, h0, nxt, Wf2 + (size_t)i * HD * HD,
                                              dinv, row_ptr, ed, beta, N);
        cur = nxt;
    }

    outm_kernel<<<LB, 256, 0, stream>>>(cur, Wfo, bo_pad, out, N);
}

// Round 15
// 338.751 us; speedup vs baseline: 3.2070x; 1.0282x over previous
//
#include <hip/hip_runtime.h>
#include <math.h>

#define HD 64
#define FIN 512
#define NC 40

struct __align__(8) EdgeT { int s; float v; };

typedef __attribute__((ext_vector_type(8))) short bf16x8;
typedef __attribute__((ext_vector_type(8))) unsigned short u16x8;
typedef __attribute__((ext_vector_type(4))) float f32x4;

__device__ __forceinline__ float bf2f(ushort u) {
    return __uint_as_float(((unsigned int)u) << 16);
}
__device__ __forceinline__ ushort f2bf(float f) {
    unsigned int u = __float_as_uint(f);
    unsigned int r = (u + 0x7fffu + ((u >> 16) & 1u)) >> 16;   // RNE
    return (ushort)r;
}

// ---------------- prep: packed8 init + all weight repacks (1 launch) ----------------
// packed8[c*n+i] (uint32): bits[26:32) = per-copy edge count, bits[0:26) =
// fixed-point(2^-21) weighted degree (max ~26 per copy << 2^26/2^21=32; exact sum).
// 32-bit atomics: R14 post-mortem showed 64-bit atomicAdd runs ~1.5x slower per op.
// frag layout: Wf[((c*4+t)*64+l)*8+j] = W[c*32+8*(l>>4)+j][t*16+(l&15)]

__global__ __launch_bounds__(256) void prep_kernel(uint* packed8, int n,
        const float* __restrict__ Win, ushort* __restrict__ Wf,
        const float* __restrict__ Wlay, ushort* __restrict__ Wf2, int L,
        const float* __restrict__ Wo, const float* __restrict__ bo,
        ushort* __restrict__ Wfo, float* __restrict__ bo_pad) {
    int i = blockIdx.x * 256 + threadIdx.x;
    if (i < 8 * n) packed8[i] = (i < n) ? (1u << 21) : 0u;  // self-loop w=1.0 in copy 0
    if (i < FIN * HD) {
        int j = i & 7, l = (i >> 3) & 63, t = (i >> 9) & 3, c = i >> 11;
        int k = c * 32 + ((l >> 4) * 8) + j;
        Wf[i] = f2bf(Win[k * HD + t * 16 + (l & 15)]);
    }
    if (i < L * HD * HD) {
        int li = i >> 12, ii = i & 4095;
        int j = ii & 7, l = (ii >> 3) & 63, t = (ii >> 9) & 3, c = (ii >> 11) & 1;
        int k = c * 32 + ((l >> 4) * 8) + j;
        Wf2[i] = f2bf(Wlay[(size_t)li * HD * HD + k * HD + t * 16 + (l & 15)]);
    }
    if (i < HD * HD) {
        int j = i & 7, l = (i >> 3) & 63, t = (i >> 9) & 3, c = (i >> 11) & 1;
        int k = c * 32 + ((l >> 4) * 8) + j;
        int col = t * 16 + (l & 15);
        Wfo[i] = (col < NC) ? f2bf(Wo[k * NC + col]) : (ushort)0;
    }
    if (i < HD) bo_pad[i] = (i < NC) ? bo[i] : 0.f;
}

// ---------------- fused: proj (MFMA, blocks < npb) || edge histogram (rest) -------

__global__ __launch_bounds__(256) void histproj_kernel(
        const int* __restrict__ dst, const float* __restrict__ w,
        uint* packed8, ushort* __restrict__ rank, int E, int n,
        const float* __restrict__ x, const ushort* __restrict__ Wf,
        const float* __restrict__ bias, ushort* __restrict__ h0, int npb) {
    if ((int)blockIdx.x >= npb) {
        int i = (blockIdx.x - npb) * 256 + threadIdx.x;
        if (i < E) {
            int d = dst[i];
            int c = i & 7;
            uint add = (1u << 26) | (uint)(w[i] * 2097152.0f);
            uint old = atomicAdd(&packed8[(size_t)c * n + d], add);
            rank[i] = (ushort)(old >> 26);
        }
        return;
    }
    const int lane = threadIdx.x & 63;
    const int wave = threadIdx.x >> 6;
    const int row = lane & 15;
    const int g = lane >> 4;
    const int base = blockIdx.x * 64 + wave * 16;

    f32x4 acc[4];
#pragma unroll
    for (int t = 0; t < 4; ++t) acc[t] = (f32x4){0.f, 0.f, 0.f, 0.f};

    int nodeA = base + row;
    if (nodeA >= n) nodeA = n - 1;
    const float* xr = x + (size_t)nodeA * FIN + g * 8;

    for (int c = 0; c < 16; ++c) {
        bf16x8 afr;
        float4 v0 = *(const float4*)(xr + c * 32);
        float4 v1 = *(const float4*)(xr + c * 32 + 4);
        afr[0] = (short)f2bf(v0.x); afr[1] = (short)f2bf(v0.y);
        afr[2] = (short)f2bf(v0.z); afr[3] = (short)f2bf(v0.w);
        afr[4] = (short)f2bf(v1.x); afr[5] = (short)f2bf(v1.y);
        afr[6] = (short)f2bf(v1.z); afr[7] = (short)f2bf(v1.w);
#pragma unroll
        for (int t = 0; t < 4; ++t) {
            bf16x8 bfr = *(const bf16x8*)(Wf + ((size_t)(c * 4 + t) * 64 + lane) * 8);
            acc[t] = __builtin_amdgcn_mfma_f32_16x16x32_bf16(afr, bfr, acc[t], 0, 0, 0);
        }
    }

    float bj[4];
#pragma unroll
    for (int t = 0; t < 4; ++t) bj[t] = bias[t * 16 + row];
#pragma unroll
    for (int r = 0; r < 4; ++r) {
        int node = base + g * 4 + r;
        if (node < n) {
#pragma unroll
            for (int t = 0; t < 4; ++t) {
                float v = fmaxf(acc[t][r] + bj[t], 0.f);
                h0[(size_t)node * HD + t * 16 + row] = f2bf(v);
            }
        }
    }
}

// fused: dinv + copy-bases (8 bytes in uint2) + per-block count scan
__global__ __launch_bounds__(256) void post_kernel(const uint* __restrict__ packed8,
        float* __restrict__ dinv, uint2* __restrict__ cbase,
        int* __restrict__ row_ptr, int* __restrict__ bsums, int n) {
    __shared__ int s[256];
    int t = threadIdx.x;
    int i = blockIdx.x * 256 + t;
    int cnt = 0;
    if (i < n) {
        int c[8];
        unsigned long long fx = 0;
#pragma unroll
        for (int k = 0; k < 8; ++k) {
            uint p = packed8[(size_t)k * n + i];
            c[k] = (int)(p >> 26);
            fx += (p & 0x3FFFFFFu);
        }
        float deg = (float)((double)fx * (1.0 / 2097152.0));
        dinv[i] = rsqrtf(deg);                     // deg >= 1 (self-loop)
        int b = 0; uint lo = 0, hi = 0;
#pragma unroll
        for (int k = 0; k < 4; ++k) { lo |= ((uint)b) << (8 * k); b += c[k]; }
#pragma unroll
        for (int k = 0; k < 4; ++k) { hi |= ((uint)b) << (8 * k); b += c[4 + k]; }
        cbase[i] = make_uint2(lo, hi);
        cnt = b;
    }
    s[t] = cnt; __syncthreads();
    for (int off = 1; off < 256; off <<= 1) {
        int u = (t >= off) ? s[t - off] : 0;
        __syncthreads();
        s[t] += u;
        __syncthreads();
    }
    if (i < n) row_ptr[i] = s[t] - cnt;
    if (t == 255) bsums[blockIdx.x] = s[255];
}

__global__ __launch_bounds__(512) void scan_top_kernel(int* bsums, int nb) {
    __shared__ int s[512];
    int t = threadIdx.x;
    int v = (t < nb) ? bsums[t] : 0;
    s[t] = v; __syncthreads();
    for (int off = 1; off < 512; off <<= 1) {
        int u = (t >= off) ? s[t - off] : 0;
        __syncthreads();
        s[t] += u;
        __syncthreads();
    }
    if (t < nb) bsums[t] = s[t] - v;
}

__global__ __launch_bounds__(256) void scan_add_kernel(int* __restrict__ row_ptr,
        const int* __restrict__ bsums, int n, int E) {
    int i = blockIdx.x * 256 + threadIdx.x;
    if (i < n) row_ptr[i] += bsums[blockIdx.x];
    if (i == 0) row_ptr[n] = E;
}

__global__ __launch_bounds__(256) void scatter_kernel(const int* __restrict__ src,
        const int* __restrict__ dst, const float* __restrict__ w,
        const float* __restrict__ dinv, const int* __restrict__ row_ptr,
        const uint2* __restrict__ cbase, const ushort* __restrict__ rank,
        EdgeT* __restrict__ ed, int E) {
    int i = blockIdx.x * 256 + threadIdx.x;
    if (i < E) {
        int s = src[i], d = dst[i];
        int c = i & 7;
        uint2 cb = cbase[d];
        int base = (int)(((c < 4) ? (cb.x >> (8 * c)) : (cb.y >> (8 * (c - 4)))) & 0xffu);
        int pos = row_ptr[d] + base + (int)rank[i];
        EdgeT e; e.s = s; e.v = dinv[s] * w[i] * dinv[d];
        ed[pos] = e;
    }
}

// ---------------- fused layer: gather(spmm) + MFMA GEMM + residual + relu --------

__global__ __launch_bounds__(256) void layerm_kernel(const ushort* __restrict__ h_in,
        const ushort* __restrict__ h0, ushort* __restrict__ h_out,
        const ushort* __restrict__ Wf2, const float* __restrict__ dinv,
        const int* __restrict__ row_ptr, const EdgeT* __restrict__ ed,
        float beta, int n) {
    __shared__ ushort S[4][32 * 72];       // 18.4 KB
    const int lane = threadIdx.x & 63;
    const int wave = threadIdx.x >> 6;
    ushort* Sw = S[wave];
    const int wbase = (blockIdx.x * 4 + wave) * 32;
    const int gs = lane >> 3;              // node slot 0..7
    const int fl = (lane & 7) * 8;         // feature offset

#pragma unroll
    for (int p = 0; p < 4; ++p) {
        int node = wbase + p * 8 + gs;
        int nc = (node < n) ? node : n - 1;
        float di = dinv[nc];
        float sw = di * di;
        u16x8 us = *(const u16x8*)(h_in + (size_t)nc * HD + fl);
        float a[8], b[8];
#pragma unroll
        for (int j = 0; j < 8; ++j) { a[j] = sw * bf2f((ushort)us[j]); b[j] = 0.f; }

        int e = row_ptr[nc], end = row_ptr[nc + 1];
        for (; e + 4 <= end; e += 4) {
            EdgeT E0 = ed[e], E1 = ed[e + 1], E2 = ed[e + 2], E3 = ed[e + 3];
            u16x8 u0 = *(const u16x8*)(h_in + (size_t)E0.s * HD + fl);
            u16x8 u1 = *(const u16x8*)(h_in + (size_t)E1.s * HD + fl);
            u16x8 u2 = *(const u16x8*)(h_in + (size_t)E2.s * HD + fl);
            u16x8 u3 = *(const u16x8*)(h_in + (size_t)E3.s * HD + fl);
#pragma unroll
            for (int j = 0; j < 8; ++j) {
                a[j] = fmaf(E0.v, bf2f((ushort)u0[j]), a[j]);
                b[j] = fmaf(E1.v, bf2f((ushort)u1[j]), b[j]);
                a[j] = fmaf(E2.v, bf2f((ushort)u2[j]), a[j]);
                b[j] = fmaf(E3.v, bf2f((ushort)u3[j]), b[j]);
            }
        }
        for (; e < end; ++e) {
            EdgeT E0 = ed[e];
            u16x8 u0 = *(const u16x8*)(h_in + (size_t)E0.s * HD + fl);
#pragma unroll
            for (int j = 0; j < 8; ++j) a[j] = fmaf(E0.v, bf2f((ushort)u0[j]), a[j]);
        }

        u16x8 uh = *(const u16x8*)(h0 + (size_t)nc * HD + fl);
        u16x8 r;
#pragma unroll
        for (int j = 0; j < 8; ++j)
            r[j] = f2bf(fmaf(0.9f, a[j] + b[j], 0.1f * bf2f((ushort)uh[j])));
        *(u16x8*)(Sw + (p * 8 + gs) * 72 + fl) = r;
    }

    asm volatile("s_waitcnt lgkmcnt(0)" ::: "memory");
    __builtin_amdgcn_wave_barrier();
    __builtin_amdgcn_sched_barrier(0);

    // ---- MFMA: 32 nodes x 64 cols ----
    const int row = lane & 15;
    const int g = lane >> 4;
    f32x4 acc[2][4];
#pragma unroll
    for (int m = 0; m < 2; ++m)
#pragma unroll
        for (int t = 0; t < 4; ++t) acc[m][t] = (f32x4){0.f, 0.f, 0.f, 0.f};

#pragma unroll
    for (int c = 0; c < 2; ++c) {
        bf16x8 afr[2];
#pragma unroll
        for (int m = 0; m < 2; ++m)
            afr[m] = *(const bf16x8*)(Sw + (m * 16 + row) * 72 + c * 32 + g * 8);
#pragma unroll
        for (int t = 0; t < 4; ++t) {
            bf16x8 bfr = *(const bf16x8*)(Wf2 + ((size_t)(c * 4 + t) * 64 + lane) * 8);
            acc[0][t] = __builtin_amdgcn_mfma_f32_16x16x32_bf16(afr[0], bfr, acc[0][t], 0, 0, 0);
            acc[1][t] = __builtin_amdgcn_mfma_f32_16x16x32_bf16(afr[1], bfr, acc[1][t], 0, 0, 0);
        }
    }

    const float ombeta = 1.f - beta;
#pragma unroll
    for (int m = 0; m < 2; ++m)
#pragma unroll
        for (int r = 0; r < 4; ++r) {
            int node = wbase + m * 16 + g * 4 + r;
            if (node < n) {
#pragma unroll
                for (int t = 0; t < 4; ++t) {
                    float sup = bf2f(Sw[(m * 16 + g * 4 + r) * 72 + t * 16 + row]);
                    float v = fmaxf(fmaf(beta, acc[m][t][r], ombeta * sup), 0.f);
                    h_out[(size_t)node * HD + t * 16 + row] = f2bf(v);
                }
            }
        }
}

// ---------------- output (MFMA) + log_softmax: out = lsm(h @ W_out + b) ----------

__global__ __launch_bounds__(256) void outm_kernel(const ushort* __restrict__ A,
        const ushort* __restrict__ Wfo, const float* __restrict__ bo_pad,
        float* __restrict__ outp, int n) {
    const int lane = threadIdx.x & 63;
    const int wave = threadIdx.x >> 6;
    const int row = lane & 15;
    const int g = lane >> 4;
    const int base = blockIdx.x * 128 + wave * 32;

    f32x4 acc[2][4];
#pragma unroll
    for (int m = 0; m < 2; ++m)
#pragma unroll
        for (int t = 0; t < 4; ++t) acc[m][t] = (f32x4){0.f, 0.f, 0.f, 0.f};

#pragma unroll
    for (int c = 0; c < 2; ++c) {
        bf16x8 afr[2];
#pragma unroll
        for (int m = 0; m < 2; ++m) {
            int node = base + m * 16 + row;
            if (node >= n) node = n - 1;
            afr[m] = *(const bf16x8*)(A + (size_t)node * HD + c * 32 + g * 8);
        }
#pragma unroll
        for (int t = 0; t < 4; ++t) {
            bf16x8 bfr = *(const bf16x8*)(Wfo + ((size_t)(c * 4 + t) * 64 + lane) * 8);
            acc[0][t] = __builtin_amdgcn_mfma_f32_16x16x32_bf16(afr[0], bfr, acc[0][t], 0, 0, 0);
            acc[1][t] = __builtin_amdgcn_mfma_f32_16x16x32_bf16(afr[1], bfr, acc[1][t], 0, 0, 0);
        }
    }

    float bj[4];
#pragma unroll
    for (int t = 0; t < 4; ++t) bj[t] = bo_pad[t * 16 + row];
    const bool v2 = (row < 8);             // col = 32+row < 40
#pragma unroll
    for (int m = 0; m < 2; ++m)
#pragma unroll
        for (int r = 0; r < 4; ++r) {
            float lo[3];
            lo[0] = acc[m][0][r] + bj[0];
            lo[1] = acc[m][1][r] + bj[1];
            lo[2] = acc[m][2][r] + bj[2];
            float mx = fmaxf(lo[0], lo[1]);
            if (v2) mx = fmaxf(mx, lo[2]);
#pragma unroll
            for (int off = 1; off < 16; off <<= 1)
                mx = fmaxf(mx, __shfl_xor(mx, off, 64));
            float s = __expf(lo[0] - mx) + __expf(lo[1] - mx);
            if (v2) s += __expf(lo[2] - mx);
#pragma unroll
            for (int off = 1; off < 16; off <<= 1)
                s += __shfl_xor(s, off, 64);
            float lse = __logf(s);
            int node = base + m * 16 + g * 4 + r;
            if (node < n) {
                outp[(size_t)node * NC + row] = lo[0] - mx - lse;
                outp[(size_t)node * NC + 16 + row] = lo[1] - mx - lse;
                if (v2) outp[(size_t)node * NC + 32 + row] = lo[2] - mx - lse;
            }
        }
}

// ---------------- launch ----------------

extern "C" void kernel_launch(void* const* d_in, const int* in_sizes, int n_in,
                              void* d_out, int out_size, void* d_ws, size_t ws_size,
                              hipStream_t stream) {
    const float* x        = (const float*)d_in[0];
    const int*   eidx     = (const int*)d_in[1];
    const float* ew       = (const float*)d_in[2];
    const float* W_in     = (const float*)d_in[3];
    const float* b_in     = (const float*)d_in[4];
    const float* W_layers = (const float*)d_in[5];
    const float* W_out    = (const float*)d_in[6];
    const float* b_out    = (const float*)d_in[7];
    float* out = (float*)d_out;

    const int N = in_sizes[0] / FIN;
    const int E = in_sizes[2];
    const int L = in_sizes[5] / (HD * HD);
    const int* src = eidx;
    const int* dst = eidx + E;

    size_t off = 0;
    auto carve = [&](size_t bytes) {
        void* p = (char*)d_ws + off;
        off += (bytes + 255) & ~(size_t)255;
        return p;
    };
    uint*   packed8 = (uint*) carve((size_t)N * 8 * 4);
    float*  dinv    = (float*)carve((size_t)N * 4);
    uint2*  cbase   = (uint2*)carve((size_t)N * 8);
    int*    row_ptr = (int*)  carve((size_t)(N + 1) * 4);
    int*    bsums   = (int*)  carve(512 * 4);
    float*  bo_pad  = (float*)carve((size_t)HD * 4);
    ushort* Wf      = (ushort*)carve((size_t)FIN * HD * 2);
    ushort* Wf2     = (ushort*)carve((size_t)L * HD * HD * 2);
    ushort* Wfo     = (ushort*)carve((size_t)HD * HD * 2);
    ushort* rank    = (ushort*)carve((size_t)E * 2);
    EdgeT*  ed      = (EdgeT*)carve((size_t)E * 8);
    ushort* h0      = (ushort*)carve((size_t)N * HD * 2);
    ushort* hA      = (ushort*)carve((size_t)N * HD * 2);
    ushort* hB      = (ushort*)carve((size_t)N * HD * 2);
    (void)ws_size;

    const int NB = (N + 255) / 256;
    const int EB = (E + 255) / 256;
    const int NPB = (N + 63) / 64;         // proj blocks

    prep_kernel<<<(8 * N + 255) / 256, 256, 0, stream>>>(packed8, N, W_in, Wf,
                                                         W_layers, Wf2, L,
                                                         W_out, b_out, Wfo, bo_pad);
    histproj_kernel<<<NPB + EB, 256, 0, stream>>>(dst, ew, packed8, rank, E, N,
                                                  x, Wf, b_in, h0, NPB);
    post_kernel<<<NB, 256, 0, stream>>>(packed8, dinv, cbase, row_ptr, bsums, N);
    scan_top_kernel<<<1, 512, 0, stream>>>(bsums, NB);
    scan_add_kernel<<<NB, 256, 0, stream>>>(row_ptr, bsums, N, E);
    scatter_kernel<<<EB, 256, 0, stream>>>(src, dst, ew, dinv, row_ptr, cbase, rank, ed, E);

    const int LB = (N + 127) / 128;        // 4 waves x 32 nodes
    const ushort* cur = h0;
    ushort* bufs[2] = { hA, hB };
    for (int i = 0; i < L; ++i) {
        float beta = logf(0.5f / (float)(i + 1) + 1.0f);
        ushort* nxt = bufs[i & 1];
        layerm_kernel<<<LB, 256, 0, stream>>>(cur, h0, nxt, Wf2 + (size_t)i * HD * HD,
                                              dinv, row_ptr, ed, beta, N);
        cur = nxt;
    }

    outm_kernel<<<LB, 256, 0, stream>>>(cur, Wfo, bo_pad, out, N);
}

// Round 16
// 333.207 us; speedup vs baseline: 3.2604x; 1.0166x over previous
//
#include <hip/hip_runtime.h>
#include <math.h>

#define HD 64
#define FIN 512
#define NC 40

struct __align__(8) EdgeT { int s; float v; };

typedef __attribute__((ext_vector_type(8))) short bf16x8;
typedef __attribute__((ext_vector_type(8))) unsigned short u16x8;
typedef __attribute__((ext_vector_type(4))) float f32x4;

__device__ __forceinline__ float bf2f(ushort u) {
    return __uint_as_float(((unsigned int)u) << 16);
}
__device__ __forceinline__ ushort f2bf(float f) {
    unsigned int u = __float_as_uint(f);
    unsigned int r = (u + 0x7fffu + ((u >> 16) & 1u)) >> 16;   // RNE
    return (ushort)r;
}

// ---------------- prep: packed8 init + all weight repacks (1 launch) ----------------
// packed8[c*n+i] (uint32): bits[26:32) = per-copy edge count, bits[0:26) =
// fixed-point(2^-21) weighted degree. frag layout:
// Wf[((c*4+t)*64+l)*8+j] = W[c*32+8*(l>>4)+j][t*16+(l&15)]

__global__ __launch_bounds__(256) void prep_kernel(uint* packed8, int n,
        const float* __restrict__ Win, ushort* __restrict__ Wf,
        const float* __restrict__ Wlay, ushort* __restrict__ Wf2, int L,
        const float* __restrict__ Wo, const float* __restrict__ bo,
        ushort* __restrict__ Wfo, float* __restrict__ bo_pad) {
    int i = blockIdx.x * 256 + threadIdx.x;
    if (i < 8 * n) packed8[i] = (i < n) ? (1u << 21) : 0u;  // self-loop w=1.0 in copy 0
    if (i < FIN * HD) {
        int j = i & 7, l = (i >> 3) & 63, t = (i >> 9) & 3, c = i >> 11;
        int k = c * 32 + ((l >> 4) * 8) + j;
        Wf[i] = f2bf(Win[k * HD + t * 16 + (l & 15)]);
    }
    if (i < L * HD * HD) {
        int li = i >> 12, ii = i & 4095;
        int j = ii & 7, l = (ii >> 3) & 63, t = (ii >> 9) & 3, c = (ii >> 11) & 1;
        int k = c * 32 + ((l >> 4) * 8) + j;
        Wf2[i] = f2bf(Wlay[(size_t)li * HD * HD + k * HD + t * 16 + (l & 15)]);
    }
    if (i < HD * HD) {
        int j = i & 7, l = (i >> 3) & 63, t = (i >> 9) & 3, c = (i >> 11) & 1;
        int k = c * 32 + ((l >> 4) * 8) + j;
        int col = t * 16 + (l & 15);
        Wfo[i] = (col < NC) ? f2bf(Wo[k * NC + col]) : (ushort)0;
    }
    if (i < HD) bo_pad[i] = (i < NC) ? bo[i] : 0.f;
}

// ---------------- fused: proj (MFMA) interleaved with edge histogram --------------
// Block role by blockIdx%k (k = grid/npb): r==0 -> proj tile q, else hist tile
// q*(k-1)+(r-1). Interleaving co-schedules atomic-latency waves with MFMA waves on
// every CU from t=0 (R15 post-mortem: tail-appended hist blocks ran serially after
// proj). Each hist thread handles 2 edges (2 atomics in flight per lane).

__global__ __launch_bounds__(256) void histproj_kernel(
        const int* __restrict__ dst, const float* __restrict__ w,
        uint* packed8, ushort* __restrict__ rank, int E, int n,
        const float* __restrict__ x, const ushort* __restrict__ Wf,
        const float* __restrict__ bias, ushort* __restrict__ h0,
        int npb, int k) {
    const int q = blockIdx.x / k;
    const int r = blockIdx.x - q * k;
    if (r != 0) {
        int hid = q * (k - 1) + (r - 1);
        int i1 = hid * 512 + threadIdx.x;
        int i2 = i1 + 256;
        if (i1 < E) {
            int d = dst[i1];
            int c = i1 & 7;
            uint add = (1u << 26) | (uint)(w[i1] * 2097152.0f);
            uint old = atomicAdd(&packed8[(size_t)c * n + d], add);
            rank[i1] = (ushort)(old >> 26);
        }
        if (i2 < E) {
            int d = dst[i2];
            int c = i2 & 7;
            uint add = (1u << 26) | (uint)(w[i2] * 2097152.0f);
            uint old = atomicAdd(&packed8[(size_t)c * n + d], add);
            rank[i2] = (ushort)(old >> 26);
        }
        return;
    }
    const int lane = threadIdx.x & 63;
    const int wave = threadIdx.x >> 6;
    const int row = lane & 15;
    const int g = lane >> 4;
    const int base = q * 64 + wave * 16;

    f32x4 acc[4];
#pragma unroll
    for (int t = 0; t < 4; ++t) acc[t] = (f32x4){0.f, 0.f, 0.f, 0.f};

    int nodeA = base + row;
    if (nodeA >= n) nodeA = n - 1;
    const float* xr = x + (size_t)nodeA * FIN + g * 8;

    for (int c = 0; c < 16; ++c) {
        bf16x8 afr;
        float4 v0 = *(const float4*)(xr + c * 32);
        float4 v1 = *(const float4*)(xr + c * 32 + 4);
        afr[0] = (short)f2bf(v0.x); afr[1] = (short)f2bf(v0.y);
        afr[2] = (short)f2bf(v0.z); afr[3] = (short)f2bf(v0.w);
        afr[4] = (short)f2bf(v1.x); afr[5] = (short)f2bf(v1.y);
        afr[6] = (short)f2bf(v1.z); afr[7] = (short)f2bf(v1.w);
#pragma unroll
        for (int t = 0; t < 4; ++t) {
            bf16x8 bfr = *(const bf16x8*)(Wf + ((size_t)(c * 4 + t) * 64 + lane) * 8);
            acc[t] = __builtin_amdgcn_mfma_f32_16x16x32_bf16(afr, bfr, acc[t], 0, 0, 0);
        }
    }

    float bj[4];
#pragma unroll
    for (int t = 0; t < 4; ++t) bj[t] = bias[t * 16 + row];
#pragma unroll
    for (int rr = 0; rr < 4; ++rr) {
        int node = base + g * 4 + rr;
        if (node < n) {
#pragma unroll
            for (int t = 0; t < 4; ++t) {
                float v = fmaxf(acc[t][rr] + bj[t], 0.f);
                h0[(size_t)node * HD + t * 16 + row] = f2bf(v);
            }
        }
    }
}

// fused: dinv + copy-bases (8 bytes in uint2) + per-block count scan
__global__ __launch_bounds__(256) void post_kernel(const uint* __restrict__ packed8,
        float* __restrict__ dinv, uint2* __restrict__ cbase,
        int* __restrict__ row_ptr, int* __restrict__ bsums, int n) {
    __shared__ int s[256];
    int t = threadIdx.x;
    int i = blockIdx.x * 256 + t;
    int cnt = 0;
    if (i < n) {
        int c[8];
        unsigned long long fx = 0;
#pragma unroll
        for (int k = 0; k < 8; ++k) {
            uint p = packed8[(size_t)k * n + i];
            c[k] = (int)(p >> 26);
            fx += (p & 0x3FFFFFFu);
        }
        float deg = (float)((double)fx * (1.0 / 2097152.0));
        dinv[i] = rsqrtf(deg);                     // deg >= 1 (self-loop)
        int b = 0; uint lo = 0, hi = 0;
#pragma unroll
        for (int k = 0; k < 4; ++k) { lo |= ((uint)b) << (8 * k); b += c[k]; }
#pragma unroll
        for (int k = 0; k < 4; ++k) { hi |= ((uint)b) << (8 * k); b += c[4 + k]; }
        cbase[i] = make_uint2(lo, hi);
        cnt = b;
    }
    s[t] = cnt; __syncthreads();
    for (int off = 1; off < 256; off <<= 1) {
        int u = (t >= off) ? s[t - off] : 0;
        __syncthreads();
        s[t] += u;
        __syncthreads();
    }
    if (i < n) row_ptr[i] = s[t] - cnt;
    if (t == 255) bsums[blockIdx.x] = s[255];
}

__global__ __launch_bounds__(512) void scan_top_kernel(int* bsums, int nb) {
    __shared__ int s[512];
    int t = threadIdx.x;
    int v = (t < nb) ? bsums[t] : 0;
    s[t] = v; __syncthreads();
    for (int off = 1; off < 512; off <<= 1) {
        int u = (t >= off) ? s[t - off] : 0;
        __syncthreads();
        s[t] += u;
        __syncthreads();
    }
    if (t < nb) bsums[t] = s[t] - v;
}

__global__ __launch_bounds__(256) void scan_add_kernel(int* __restrict__ row_ptr,
        const int* __restrict__ bsums, int n, int E) {
    int i = blockIdx.x * 256 + threadIdx.x;
    if (i < n) row_ptr[i] += bsums[blockIdx.x];
    if (i == 0) row_ptr[n] = E;
}

__global__ __launch_bounds__(256) void scatter_kernel(const int* __restrict__ src,
        const int* __restrict__ dst, const float* __restrict__ w,
        const float* __restrict__ dinv, const int* __restrict__ row_ptr,
        const uint2* __restrict__ cbase, const ushort* __restrict__ rank,
        EdgeT* __restrict__ ed, int E) {
    int i = blockIdx.x * 256 + threadIdx.x;
    if (i < E) {
        int s = src[i], d = dst[i];
        int c = i & 7;
        uint2 cb = cbase[d];
        int base = (int)(((c < 4) ? (cb.x >> (8 * c)) : (cb.y >> (8 * (c - 4)))) & 0xffu);
        int pos = row_ptr[d] + base + (int)rank[i];
        EdgeT e; e.s = s; e.v = dinv[s] * w[i] * dinv[d];
        ed[pos] = e;
    }
}

// ---------------- fused layer: gather(spmm) + MFMA GEMM + residual + relu --------

__global__ __launch_bounds__(256) void layerm_kernel(const ushort* __restrict__ h_in,
        const ushort* __restrict__ h0, ushort* __restrict__ h_out,
        const ushort* __restrict__ Wf2, const float* __restrict__ dinv,
        const int* __restrict__ row_ptr, const EdgeT* __restrict__ ed,
        float beta, int n) {
    __shared__ ushort S[4][32 * 72];       // 18.4 KB
    const int lane = threadIdx.x & 63;
    const int wave = threadIdx.x >> 6;
    ushort* Sw = S[wave];
    const int wbase = (blockIdx.x * 4 + wave) * 32;
    const int gs = lane >> 3;              // node slot 0..7
    const int fl = (lane & 7) * 8;         // feature offset

#pragma unroll
    for (int p = 0; p < 4; ++p) {
        int node = wbase + p * 8 + gs;
        int nc = (node < n) ? node : n - 1;
        float di = dinv[nc];
        float sw = di * di;
        u16x8 us = *(const u16x8*)(h_in + (size_t)nc * HD + fl);
        float a[8], b[8];
#pragma unroll
        for (int j = 0; j < 8; ++j) { a[j] = sw * bf2f((ushort)us[j]); b[j] = 0.f; }

        int e = row_ptr[nc], end = row_ptr[nc + 1];
        for (; e + 4 <= end; e += 4) {
            EdgeT E0 = ed[e], E1 = ed[e + 1], E2 = ed[e + 2], E3 = ed[e + 3];
            u16x8 u0 = *(const u16x8*)(h_in + (size_t)E0.s * HD + fl);
            u16x8 u1 = *(const u16x8*)(h_in + (size_t)E1.s * HD + fl);
            u16x8 u2 = *(const u16x8*)(h_in + (size_t)E2.s * HD + fl);
            u16x8 u3 = *(const u16x8*)(h_in + (size_t)E3.s * HD + fl);
#pragma unroll
            for (int j = 0; j < 8; ++j) {
                a[j] = fmaf(E0.v, bf2f((ushort)u0[j]), a[j]);
                b[j] = fmaf(E1.v, bf2f((ushort)u1[j]), b[j]);
                a[j] = fmaf(E2.v, bf2f((ushort)u2[j]), a[j]);
                b[j] = fmaf(E3.v, bf2f((ushort)u3[j]), b[j]);
            }
        }
        for (; e < end; ++e) {
            EdgeT E0 = ed[e];
            u16x8 u0 = *(const u16x8*)(h_in + (size_t)E0.s * HD + fl);
#pragma unroll
            for (int j = 0; j < 8; ++j) a[j] = fmaf(E0.v, bf2f((ushort)u0[j]), a[j]);
        }

        u16x8 uh = *(const u16x8*)(h0 + (size_t)nc * HD + fl);
        u16x8 r;
#pragma unroll
        for (int j = 0; j < 8; ++j)
            r[j] = f2bf(fmaf(0.9f, a[j] + b[j], 0.1f * bf2f((ushort)uh[j])));
        *(u16x8*)(Sw + (p * 8 + gs) * 72 + fl) = r;
    }

    asm volatile("s_waitcnt lgkmcnt(0)" ::: "memory");
    __builtin_amdgcn_wave_barrier();
    __builtin_amdgcn_sched_barrier(0);

    // ---- MFMA: 32 nodes x 64 cols ----
    const int row = lane & 15;
    const int g = lane >> 4;
    f32x4 acc[2][4];
#pragma unroll
    for (int m = 0; m < 2; ++m)
#pragma unroll
        for (int t = 0; t < 4; ++t) acc[m][t] = (f32x4){0.f, 0.f, 0.f, 0.f};

#pragma unroll
    for (int c = 0; c < 2; ++c) {
        bf16x8 afr[2];
#pragma unroll
        for (int m = 0; m < 2; ++m)
            afr[m] = *(const bf16x8*)(Sw + (m * 16 + row) * 72 + c * 32 + g * 8);
#pragma unroll
        for (int t = 0; t < 4; ++t) {
            bf16x8 bfr = *(const bf16x8*)(Wf2 + ((size_t)(c * 4 + t) * 64 + lane) * 8);
            acc[0][t] = __builtin_amdgcn_mfma_f32_16x16x32_bf16(afr[0], bfr, acc[0][t], 0, 0, 0);
            acc[1][t] = __builtin_amdgcn_mfma_f32_16x16x32_bf16(afr[1], bfr, acc[1][t], 0, 0, 0);
        }
    }

    const float ombeta = 1.f - beta;
#pragma unroll
    for (int m = 0; m < 2; ++m)
#pragma unroll
        for (int r = 0; r < 4; ++r) {
            int node = wbase + m * 16 + g * 4 + r;
            if (node < n) {
#pragma unroll
                for (int t = 0; t < 4; ++t) {
                    float sup = bf2f(Sw[(m * 16 + g * 4 + r) * 72 + t * 16 + row]);
                    float v = fmaxf(fmaf(beta, acc[m][t][r], ombeta * sup), 0.f);
                    h_out[(size_t)node * HD + t * 16 + row] = f2bf(v);
                }
            }
        }
}

// ---------------- output (MFMA) + log_softmax: out = lsm(h @ W_out + b) ----------

__global__ __launch_bounds__(256) void outm_kernel(const ushort* __restrict__ A,
        const ushort* __restrict__ Wfo, const float* __restrict__ bo_pad,
        float* __restrict__ outp, int n) {
    const int lane = threadIdx.x & 63;
    const int wave = threadIdx.x >> 6;
    const int row = lane & 15;
    const int g = lane >> 4;
    const int base = blockIdx.x * 128 + wave * 32;

    f32x4 acc[2][4];
#pragma unroll
    for (int m = 0; m < 2; ++m)
#pragma unroll
        for (int t = 0; t < 4; ++t) acc[m][t] = (f32x4){0.f, 0.f, 0.f, 0.f};

#pragma unroll
    for (int c = 0; c < 2; ++c) {
        bf16x8 afr[2];
#pragma unroll
        for (int m = 0; m < 2; ++m) {
            int node = base + m * 16 + row;
            if (node >= n) node = n - 1;
            afr[m] = *(const bf16x8*)(A + (size_t)node * HD + c * 32 + g * 8);
        }
#pragma unroll
        for (int t = 0; t < 4; ++t) {
            bf16x8 bfr = *(const bf16x8*)(Wfo + ((size_t)(c * 4 + t) * 64 + lane) * 8);
            acc[0][t] = __builtin_amdgcn_mfma_f32_16x16x32_bf16(afr[0], bfr, acc[0][t], 0, 0, 0);
            acc[1][t] = __builtin_amdgcn_mfma_f32_16x16x32_bf16(afr[1], bfr, acc[1][t], 0, 0, 0);
        }
    }

    float bj[4];
#pragma unroll
    for (int t = 0; t < 4; ++t) bj[t] = bo_pad[t * 16 + row];
    const bool v2 = (row < 8);             // col = 32+row < 40
#pragma unroll
    for (int m = 0; m < 2; ++m)
#pragma unroll
        for (int r = 0; r < 4; ++r) {
            float lo[3];
            lo[0] = acc[m][0][r] + bj[0];
            lo[1] = acc[m][1][r] + bj[1];
            lo[2] = acc[m][2][r] + bj[2];
            float mx = fmaxf(lo[0], lo[1]);
            if (v2) mx = fmaxf(mx, lo[2]);
#pragma unroll
            for (int off = 1; off < 16; off <<= 1)
                mx = fmaxf(mx, __shfl_xor(mx, off, 64));
            float s = __expf(lo[0] - mx) + __expf(lo[1] - mx);
            if (v2) s += __expf(lo[2] - mx);
#pragma unroll
            for (int off = 1; off < 16; off <<= 1)
                s += __shfl_xor(s, off, 64);
            float lse = __logf(s);
            int node = base + m * 16 + g * 4 + r;
            if (node < n) {
                outp[(size_t)node * NC + row] = lo[0] - mx - lse;
                outp[(size_t)node * NC + 16 + row] = lo[1] - mx - lse;
                if (v2) outp[(size_t)node * NC + 32 + row] = lo[2] - mx - lse;
            }
        }
}

// ---------------- launch ----------------

extern "C" void kernel_launch(void* const* d_in, const int* in_sizes, int n_in,
                              void* d_out, int out_size, void* d_ws, size_t ws_size,
                              hipStream_t stream) {
    const float* x        = (const float*)d_in[0];
    const int*   eidx     = (const int*)d_in[1];
    const float* ew       = (const float*)d_in[2];
    const float* W_in     = (const float*)d_in[3];
    const float* b_in     = (const float*)d_in[4];
    const float* W_layers = (const float*)d_in[5];
    const float* W_out    = (const float*)d_in[6];
    const float* b_out    = (const float*)d_in[7];
    float* out = (float*)d_out;

    const int N = in_sizes[0] / FIN;
    const int E = in_sizes[2];
    const int L = in_sizes[5] / (HD * HD);
    const int* src = eidx;
    const int* dst = eidx + E;

    size_t off = 0;
    auto carve = [&](size_t bytes) {
        void* p = (char*)d_ws + off;
        off += (bytes + 255) & ~(size_t)255;
        return p;
    };
    uint*   packed8 = (uint*) carve((size_t)N * 8 * 4);
    float*  dinv    = (float*)carve((size_t)N * 4);
    uint2*  cbase   = (uint2*)carve((size_t)N * 8);
    int*    row_ptr = (int*)  carve((size_t)(N + 1) * 4);
    int*    bsums   = (int*)  carve(512 * 4);
    float*  bo_pad  = (float*)carve((size_t)HD * 4);
    ushort* Wf      = (ushort*)carve((size_t)FIN * HD * 2);
    ushort* Wf2     = (ushort*)carve((size_t)L * HD * HD * 2);
    ushort* Wfo     = (ushort*)carve((size_t)HD * HD * 2);
    ushort* rank    = (ushort*)carve((size_t)E * 2);
    EdgeT*  ed      = (EdgeT*)carve((size_t)E * 8);
    ushort* h0      = (ushort*)carve((size_t)N * HD * 2);
    ushort* hA      = (ushort*)carve((size_t)N * HD * 2);
    ushort* hB      = (ushort*)carve((size_t)N * HD * 2);
    (void)ws_size;

    const int NB = (N + 255) / 256;
    const int EB = (E + 255) / 256;
    const int NPB = (N + 63) / 64;           // proj blocks
    const int HB  = (E + 511) / 512;         // hist blocks (2 edges/thread)
    const int K   = (NPB + HB + NPB - 1) / NPB;   // interleave stride
    const int GRID = NPB * K;                // proj at r==0, hist slots >= HB idle

    prep_kernel<<<(8 * N + 255) / 256, 256, 0, stream>>>(packed8, N, W_in, Wf,
                                                         W_layers, Wf2, L,
                                                         W_out, b_out, Wfo, bo_pad);
    histproj_kernel<<<GRID, 256, 0, stream>>>(dst, ew, packed8, rank, E, N,
                                              x, Wf, b_in, h0, NPB, K);
    post_kernel<<<NB, 256, 0, stream>>>(packed8, dinv, cbase, row_ptr, bsums, N);
    scan_top_kernel<<<1, 512, 0, stream>>>(bsums, NB);
    scan_add_kernel<<<NB, 256, 0, stream>>>(row_ptr, bsums, N, E);
    scatter_kernel<<<EB, 256, 0, stream>>>(src, dst, ew, dinv, row_ptr, cbase, rank, ed, E);

    const int LB = (N + 127) / 128;          // 4 waves x 32 nodes
    const ushort* cur = h0;
    ushort* bufs[2] = { hA, hB };
    for (int i = 0; i < L; ++i) {
        float beta = logf(0.5f / (float)(i + 1) + 1.0f);
        ushort* nxt = bufs[i & 1];
        layerm_kernel<<<LB, 256, 0, stream>>>(cur, h0, nxt, Wf2 + (size_t)i * HD * HD,
                                              dinv, row_ptr, ed, beta, N);
        cur = nxt;
    }

    outm_kernel<<<LB, 256, 0, stream>>>(cur, Wfo, bo_pad, out, N);
}